// Round 1
// baseline (2035.202 us; speedup 1.0000x reference)
//
#include <hip/hip_runtime.h>

constexpr int NN    = 128;
constexpr int BB    = 2;
constexpr int DIN   = 128;
constexpr int DD    = 256;
constexpr int DFF   = 1024;
constexpr int NH    = 8;
constexpr int DH    = 32;
constexpr int NL    = 2;
constexpr int BLK   = 32;
constexpr int WMAX  = 2 * BLK + 1;       // 65
constexpr int RROWS = NN * WMAX * BB;    // 16640
constexpr int TR    = 16;                // rows per block in GEMM kernels

// ---------------------------------------------------------------------------
// K0: kp = relu(inputs @ k_W1 + k_b1) @ k_W2 + k_b2     (N*B rows of dim 2)
// ---------------------------------------------------------------------------
__global__ __launch_bounds__(256) void k_kp(
    const float* __restrict__ inp, const float* __restrict__ kW1,
    const float* __restrict__ kb1, const float* __restrict__ kW2,
    const float* __restrict__ kb2, float* __restrict__ kp) {
  __shared__ float xs[DIN];
  __shared__ float red[8];
  int row = blockIdx.x;          // n*BB + b
  int tid = threadIdx.x;
  if (tid < DIN) xs[tid] = inp[row * DIN + tid];
  __syncthreads();
  float a0 = 0.f, a1 = 0.f;
  for (int j = tid; j < DFF; j += 256) {
    float acc = kb1[j];
    for (int k = 0; k < DIN; ++k) acc += xs[k] * kW1[k * DFF + j];
    acc = fmaxf(acc, 0.f);
    a0 += acc * kW2[2 * j];
    a1 += acc * kW2[2 * j + 1];
  }
#pragma unroll
  for (int m = 32; m > 0; m >>= 1) {
    a0 += __shfl_xor(a0, m, 64);
    a1 += __shfl_xor(a1, m, 64);
  }
  if ((tid & 63) == 0) { red[(tid >> 6) * 2] = a0; red[(tid >> 6) * 2 + 1] = a1; }
  __syncthreads();
  if (tid == 0) {
    kp[row * 2 + 0] = red[0] + red[2] + red[4] + red[6] + kb2[0];
    kp[row * 2 + 1] = red[1] + red[3] + red[5] + red[7] + kb2[1];
  }
}

// ---------------------------------------------------------------------------
// K1: input MLP  h = relu(x @ in_W1 + b1) @ in_W2 + b2, x = inputs + PE
// ---------------------------------------------------------------------------
__global__ __launch_bounds__(256) void k_inmlp(
    const float* __restrict__ inp, const float* __restrict__ Wa,
    const float* __restrict__ ba, const float* __restrict__ Wb,
    const float* __restrict__ bb, float* __restrict__ h) {
  __shared__ float xs[TR][DIN];     // 8 KB
  __shared__ float ts[TR][68];      // padded to 68 for 16B-aligned rows
  int tid = threadIdx.x;
  int r0 = blockIdx.x * TR;
  // stage x tile with positional encoding computed on the fly
  for (int e = tid; e < TR * DIN; e += 256) {
    int rr = e >> 7, i = e & 127;
    int r = r0 + rr;
    int n = r / (WMAX * BB);
    int rem = r % (WMAX * BB);
    int w = rem >> 1, b = rem & 1;
    int st = n - BLK; if (st < 0) st = 0;
    float pos = (float)(st + w);
    float div = __expf(-0.0719557841f * (float)(i & 126)); // -ln(1e4)/128 * 2i
    float ang = pos * div;
    float pe = (i & 1) ? __cosf(ang) : __sinf(ang);
    xs[rr][i] = inp[(n * BB + b) * DIN + i] + pe;
  }
  __syncthreads();
  int lane = tid & 63, wv = tid >> 6;
  float hacc[TR];
#pragma unroll
  for (int rr = 0; rr < TR; ++rr) hacc[rr] = 0.f;
  for (int ch = 0; ch < DFF; ch += 64) {
    float t4[4];
#pragma unroll
    for (int q = 0; q < 4; ++q) t4[q] = ba[ch + lane];
    for (int k4 = 0; k4 < DIN / 4; ++k4) {
      float w1v[4];
#pragma unroll
      for (int u = 0; u < 4; ++u) w1v[u] = Wa[(k4 * 4 + u) * DFF + ch + lane];
#pragma unroll
      for (int q = 0; q < 4; ++q) {
        float4 xv = *reinterpret_cast<const float4*>(&xs[wv * 4 + q][k4 * 4]);
        t4[q] += xv.x * w1v[0] + xv.y * w1v[1] + xv.z * w1v[2] + xv.w * w1v[3];
      }
    }
#pragma unroll
    for (int q = 0; q < 4; ++q) ts[wv * 4 + q][lane] = fmaxf(t4[q], 0.f);
    __syncthreads();
    for (int k4 = 0; k4 < 16; ++k4) {
      float w2v[4];
#pragma unroll
      for (int u = 0; u < 4; ++u) w2v[u] = Wb[(ch + k4 * 4 + u) * DD + tid];
#pragma unroll
      for (int rr = 0; rr < TR; ++rr) {
        float4 tv = *reinterpret_cast<const float4*>(&ts[rr][k4 * 4]);
        hacc[rr] += tv.x * w2v[0] + tv.y * w2v[1] + tv.z * w2v[2] + tv.w * w2v[3];
      }
    }
    __syncthreads();
  }
  float b2v = bb[tid];
#pragma unroll
  for (int rr = 0; rr < TR; ++rr) h[(size_t)(r0 + rr) * DD + tid] = hacc[rr] + b2v;
}

// ---------------------------------------------------------------------------
// K2: qkv = h @ Wqkv[l] + bqkv[l]    (R x 256) @ (256 x 768)
// ---------------------------------------------------------------------------
__global__ __launch_bounds__(256) void k_qkv(
    const float* __restrict__ h, const float* __restrict__ Wq,
    const float* __restrict__ bq, float* __restrict__ qkv) {
  __shared__ float hs[TR][DD];      // 16 KB
  int tid = threadIdx.x;
  int r0 = blockIdx.x * TR;
  for (int e = tid; e < TR * DD; e += 256)
    hs[e >> 8][e & 255] = h[(size_t)(r0 + (e >> 8)) * DD + (e & 255)];
  __syncthreads();
  float acc[TR][3];
#pragma unroll
  for (int rr = 0; rr < TR; ++rr)
#pragma unroll
    for (int j = 0; j < 3; ++j) acc[rr][j] = bq[tid + j * 256];
  for (int k4 = 0; k4 < DD / 4; ++k4) {
    float wv[4][3];
#pragma unroll
    for (int u = 0; u < 4; ++u)
#pragma unroll
      for (int j = 0; j < 3; ++j) wv[u][j] = Wq[(size_t)(k4 * 4 + u) * (3 * DD) + tid + j * 256];
#pragma unroll
    for (int rr = 0; rr < TR; ++rr) {
      float4 hv = *reinterpret_cast<const float4*>(&hs[rr][k4 * 4]);
#pragma unroll
      for (int j = 0; j < 3; ++j)
        acc[rr][j] += hv.x * wv[0][j] + hv.y * wv[1][j] + hv.z * wv[2][j] + hv.w * wv[3][j];
    }
  }
#pragma unroll
  for (int rr = 0; rr < TR; ++rr)
#pragma unroll
    for (int j = 0; j < 3; ++j)
      qkv[(size_t)(r0 + rr) * (3 * DD) + tid + j * 256] = acc[rr][j];
}

// ---------------------------------------------------------------------------
// K3: windowed attention per (n, b, head).  One thread = one q row.
// ---------------------------------------------------------------------------
__global__ __launch_bounds__(128) void k_attn(
    const float* __restrict__ qkv, float* __restrict__ o,
    const int* __restrict__ lenp) {
  int L = lenp[0];
  int blk = blockIdx.x;
  int hh = blk & 7;
  int nb = blk >> 3;
  int b = nb & 1;
  int n = nb >> 1;
  int s0 = n - BLK; if (s0 < 0) s0 = 0;
  int e0 = n + BLK + 1; if (e0 > L) e0 = L;
  int vn = e0 - s0;                // number of valid cols (>= 33)
  __shared__ float kt[WMAX][DH];
  __shared__ float vt[WMAX][DH];
  int tid = threadIdx.x;
  for (int e = tid; e < WMAX * DH; e += 128) {
    int w = e >> 5, d = e & 31;
    const float* rowp = qkv + (size_t)((n * WMAX + w) * BB + b) * (3 * DD);
    kt[w][d] = rowp[DD + hh * DH + d];
    vt[w][d] = rowp[2 * DD + hh * DH + d];
  }
  __syncthreads();
  int q = tid;
  if (q < WMAX) {
    const float* qp = qkv + (size_t)((n * WMAX + q) * BB + b) * (3 * DD) + hh * DH;
    float4 qv[8];
#pragma unroll
    for (int u = 0; u < 8; ++u) qv[u] = reinterpret_cast<const float4*>(qp)[u];
    float s[WMAX];
    float mx = -3e38f;
#pragma unroll
    for (int j = 0; j < WMAX; ++j) {
      float acc = 0.f;
      const float4* kr = reinterpret_cast<const float4*>(kt[j]);
#pragma unroll
      for (int u = 0; u < 8; ++u) {
        float4 kv = kr[u];
        acc += qv[u].x * kv.x + qv[u].y * kv.y + qv[u].z * kv.z + qv[u].w * kv.w;
      }
      acc *= 0.17677669529663687f;  // 1/sqrt(32)
      s[j] = acc;
      mx = (j < vn) ? fmaxf(mx, acc) : mx;
    }
    float sum = 0.f;
#pragma unroll
    for (int j = 0; j < WMAX; ++j) {
      float p = (j < vn) ? __expf(s[j] - mx) : 0.f;
      s[j] = p;
      sum += p;
    }
    float inv = 1.f / sum;
    float4 ov[8];
#pragma unroll
    for (int u = 0; u < 8; ++u) ov[u] = make_float4(0.f, 0.f, 0.f, 0.f);
#pragma unroll
    for (int j = 0; j < WMAX; ++j) {
      float p = s[j];
      const float4* vr = reinterpret_cast<const float4*>(vt[j]);
#pragma unroll
      for (int u = 0; u < 8; ++u) {
        float4 vv = vr[u];
        ov[u].x += p * vv.x; ov[u].y += p * vv.y; ov[u].z += p * vv.z; ov[u].w += p * vv.w;
      }
    }
    float* op = o + (size_t)((n * WMAX + q) * BB + b) * DD + hh * DH;
#pragma unroll
    for (int u = 0; u < 8; ++u) {
      float4 r = make_float4(ov[u].x * inv, ov[u].y * inv, ov[u].z * inv, ov[u].w * inv);
      reinterpret_cast<float4*>(op)[u] = r;
    }
  }
}

// ---------------------------------------------------------------------------
// K4: h = LN(h + o @ Wo + bo)
// ---------------------------------------------------------------------------
__global__ __launch_bounds__(256) void k_oproj_ln(
    const float* __restrict__ o, const float* __restrict__ Wo,
    const float* __restrict__ bo, const float* __restrict__ g,
    const float* __restrict__ be, float* __restrict__ h) {
  __shared__ float os[TR][DD];
  __shared__ float vt[TR][DD];
  __shared__ float mr[TR][2];
  int tid = threadIdx.x;
  int r0 = blockIdx.x * TR;
  for (int e = tid; e < TR * DD; e += 256)
    os[e >> 8][e & 255] = o[(size_t)(r0 + (e >> 8)) * DD + (e & 255)];
  __syncthreads();
  float acc[TR];
#pragma unroll
  for (int rr = 0; rr < TR; ++rr) acc[rr] = 0.f;
  for (int k4 = 0; k4 < DD / 4; ++k4) {
    float wv[4];
#pragma unroll
    for (int u = 0; u < 4; ++u) wv[u] = Wo[(size_t)(k4 * 4 + u) * DD + tid];
#pragma unroll
    for (int rr = 0; rr < TR; ++rr) {
      float4 ovv = *reinterpret_cast<const float4*>(&os[rr][k4 * 4]);
      acc[rr] += ovv.x * wv[0] + ovv.y * wv[1] + ovv.z * wv[2] + ovv.w * wv[3];
    }
  }
  float bov = bo[tid];
#pragma unroll
  for (int rr = 0; rr < TR; ++rr)
    vt[rr][tid] = acc[rr] + bov + h[(size_t)(r0 + rr) * DD + tid];
  __syncthreads();
  int rw = tid >> 4, l16 = tid & 15;
  float sm = 0.f, sq = 0.f;
#pragma unroll
  for (int i = 0; i < 16; ++i) {
    float v = vt[rw][l16 + 16 * i];
    sm += v; sq += v * v;
  }
#pragma unroll
  for (int m = 1; m < 16; m <<= 1) { sm += __shfl_xor(sm, m, 16); sq += __shfl_xor(sq, m, 16); }
  if (l16 == 0) {
    float mean = sm * (1.f / DD);
    float var = sq * (1.f / DD) - mean * mean;
    mr[rw][0] = mean;
    mr[rw][1] = rsqrtf(var + 1e-5f);
  }
  __syncthreads();
  float gg = g[tid], bbv = be[tid];
#pragma unroll
  for (int rr = 0; rr < TR; ++rr) {
    float v = vt[rr][tid];
    h[(size_t)(r0 + rr) * DD + tid] = (v - mr[rr][0]) * mr[rr][1] * gg + bbv;
  }
}

// ---------------------------------------------------------------------------
// K5: h = LN(h + relu(h @ W1 + b1) @ W2 + b2)
// ---------------------------------------------------------------------------
__global__ __launch_bounds__(256) void k_ffn_ln(
    const float* __restrict__ W1p, const float* __restrict__ b1p,
    const float* __restrict__ W2p, const float* __restrict__ b2p,
    const float* __restrict__ g, const float* __restrict__ be,
    float* __restrict__ h) {
  __shared__ float hs[TR][DD];      // 16 KB, holds pre-FFN h for residual
  __shared__ float ts[TR][68];
  __shared__ float vt[TR][DD];
  __shared__ float mr[TR][2];
  int tid = threadIdx.x;
  int r0 = blockIdx.x * TR;
  for (int e = tid; e < TR * DD; e += 256)
    hs[e >> 8][e & 255] = h[(size_t)(r0 + (e >> 8)) * DD + (e & 255)];
  __syncthreads();
  int lane = tid & 63, wv4 = tid >> 6;
  float facc[TR];
#pragma unroll
  for (int rr = 0; rr < TR; ++rr) facc[rr] = 0.f;
  for (int ch = 0; ch < DFF; ch += 64) {
    float t4[4];
#pragma unroll
    for (int q = 0; q < 4; ++q) t4[q] = b1p[ch + lane];
    for (int k4 = 0; k4 < DD / 4; ++k4) {
      float w1v[4];
#pragma unroll
      for (int u = 0; u < 4; ++u) w1v[u] = W1p[(size_t)(k4 * 4 + u) * DFF + ch + lane];
#pragma unroll
      for (int q = 0; q < 4; ++q) {
        float4 hv = *reinterpret_cast<const float4*>(&hs[wv4 * 4 + q][k4 * 4]);
        t4[q] += hv.x * w1v[0] + hv.y * w1v[1] + hv.z * w1v[2] + hv.w * w1v[3];
      }
    }
#pragma unroll
    for (int q = 0; q < 4; ++q) ts[wv4 * 4 + q][lane] = fmaxf(t4[q], 0.f);
    __syncthreads();
    for (int k4 = 0; k4 < 16; ++k4) {
      float w2v[4];
#pragma unroll
      for (int u = 0; u < 4; ++u) w2v[u] = W2p[(size_t)(ch + k4 * 4 + u) * DD + tid];
#pragma unroll
      for (int rr = 0; rr < TR; ++rr) {
        float4 tv = *reinterpret_cast<const float4*>(&ts[rr][k4 * 4]);
        facc[rr] += tv.x * w2v[0] + tv.y * w2v[1] + tv.z * w2v[2] + tv.w * w2v[3];
      }
    }
    __syncthreads();
  }
  float b2v = b2p[tid];
#pragma unroll
  for (int rr = 0; rr < TR; ++rr)
    vt[rr][tid] = facc[rr] + b2v + hs[rr][tid];
  __syncthreads();
  int rw = tid >> 4, l16 = tid & 15;
  float sm = 0.f, sq = 0.f;
#pragma unroll
  for (int i = 0; i < 16; ++i) {
    float v = vt[rw][l16 + 16 * i];
    sm += v; sq += v * v;
  }
#pragma unroll
  for (int m = 1; m < 16; m <<= 1) { sm += __shfl_xor(sm, m, 16); sq += __shfl_xor(sq, m, 16); }
  if (l16 == 0) {
    float mean = sm * (1.f / DD);
    float var = sq * (1.f / DD) - mean * mean;
    mr[rw][0] = mean;
    mr[rw][1] = rsqrtf(var + 1e-5f);
  }
  __syncthreads();
  float gg = g[tid], bbv = be[tid];
#pragma unroll
  for (int rr = 0; rr < TR; ++rr) {
    float v = vt[rr][tid];
    h[(size_t)(r0 + rr) * DD + tid] = (v - mr[rr][0]) * mr[rr][1] * gg + bbv;
  }
}

// ---------------------------------------------------------------------------
// K6: final hierarchical softmax-gather over tokens
// ---------------------------------------------------------------------------
__global__ __launch_bounds__(256) void k_final(
    const float* __restrict__ h, const float* __restrict__ kp,
    float* __restrict__ out, const int* __restrict__ lenp) {
  int L = lenp[0];
  int t = blockIdx.x >> 1, b = blockIdx.x & 1;
  float hsc = (float)L / (float)NN;
  int nlo = t - 2 * BLK < 0 ? 0 : t - BLK; // placeholder, fixed below
  nlo = t - BLK; if (nlo < 0) nlo = 0;
  int nhi = t + BLK; if (nhi > NN - 1) nhi = NN - 1;
  float mx = -3e38f;
  for (int n = nlo; n <= nhi; ++n) {
    float kp0 = kp[(n * BB + b) * 2 + 0];
    float kp1 = kp[(n * BB + b) * 2 + 1];
    float dif = (float)t - (float)n * hsc - kp0;
    float lg = -dif * dif * __expf(kp1);
    mx = fmaxf(mx, lg);
  }
  float sum = 0.f, acc = 0.f;
  int c = threadIdx.x;
  for (int n = nlo; n <= nhi; ++n) {
    float kp0 = kp[(n * BB + b) * 2 + 0];
    float kp1 = kp[(n * BB + b) * 2 + 1];
    float dif = (float)t - (float)n * hsc - kp0;
    float lg = -dif * dif * __expf(kp1);
    float p = __expf(lg - mx);
    sum += p;
    int st = n - BLK; if (st < 0) st = 0;
    int w = t - st;
    acc += p * h[(size_t)((n * WMAX + w) * BB + b) * DD + c];
  }
  out[(size_t)(t * BB + b) * DD + c] = acc / sum;
}

// ---------------------------------------------------------------------------
extern "C" void kernel_launch(void* const* d_in, const int* in_sizes, int n_in,
                              void* d_out, int out_size, void* d_ws, size_t ws_size,
                              hipStream_t stream) {
  const float* inputs = (const float*)d_in[0];
  const float* in_W1  = (const float*)d_in[1];
  const float* in_b1  = (const float*)d_in[2];
  const float* in_W2  = (const float*)d_in[3];
  const float* in_b2  = (const float*)d_in[4];
  const float* k_W1   = (const float*)d_in[5];
  const float* k_b1   = (const float*)d_in[6];
  const float* k_W2   = (const float*)d_in[7];
  const float* k_b2   = (const float*)d_in[8];
  const float* Wqkv   = (const float*)d_in[9];
  const float* bqkv   = (const float*)d_in[10];
  const float* Wo     = (const float*)d_in[11];
  const float* bo     = (const float*)d_in[12];
  const float* ln1_g  = (const float*)d_in[13];
  const float* ln1_b  = (const float*)d_in[14];
  const float* W1     = (const float*)d_in[15];
  const float* b1     = (const float*)d_in[16];
  const float* W2     = (const float*)d_in[17];
  const float* b2     = (const float*)d_in[18];
  const float* ln2_g  = (const float*)d_in[19];
  const float* ln2_b  = (const float*)d_in[20];
  const int*   lenp   = (const int*)d_in[21];
  float* out = (float*)d_out;

  float* ws  = (float*)d_ws;
  float* kp  = ws;                                   // 512 floats
  float* h   = ws + 1024;                            // RROWS*DD
  float* o   = h + (size_t)RROWS * DD;               // RROWS*DD
  float* qkv = o + (size_t)RROWS * DD;               // RROWS*3*DD
  (void)in_sizes; (void)n_in; (void)ws_size;

  int L = out_size / (BB * DD);                      // 160

  k_kp<<<NN * BB, 256, 0, stream>>>(inputs, k_W1, k_b1, k_W2, k_b2, kp);
  k_inmlp<<<RROWS / TR, 256, 0, stream>>>(inputs, in_W1, in_b1, in_W2, in_b2, h);
  for (int l = 0; l < NL; ++l) {
    k_qkv<<<RROWS / TR, 256, 0, stream>>>(h, Wqkv + (size_t)l * DD * 3 * DD,
                                          bqkv + (size_t)l * 3 * DD, qkv);
    k_attn<<<NN * BB * NH, 128, 0, stream>>>(qkv, o, lenp);
    k_oproj_ln<<<RROWS / TR, 256, 0, stream>>>(o, Wo + (size_t)l * DD * DD,
                                               bo + (size_t)l * DD,
                                               ln1_g + (size_t)l * DD,
                                               ln1_b + (size_t)l * DD, h);
    k_ffn_ln<<<RROWS / TR, 256, 0, stream>>>(W1 + (size_t)l * DD * DFF,
                                             b1 + (size_t)l * DFF,
                                             W2 + (size_t)l * DFF * DD,
                                             b2 + (size_t)l * DD,
                                             ln2_g + (size_t)l * DD,
                                             ln2_b + (size_t)l * DD, h);
  }
  k_final<<<L * BB, 256, 0, stream>>>(h, kp, out, lenp);
}

// Round 2
// 445.562 us; speedup vs baseline: 4.5677x; 4.5677x over previous
//
#include <hip/hip_runtime.h>

constexpr int NN    = 128;
constexpr int BB    = 2;
constexpr int DIN   = 128;
constexpr int DD    = 256;
constexpr int DFF   = 1024;
constexpr int NH    = 8;
constexpr int DH    = 32;
constexpr int NL    = 2;
constexpr int BLK   = 32;
constexpr int WMAX  = 2 * BLK + 1;       // 65
constexpr int RROWS = NN * WMAX * BB;    // 16640

typedef __attribute__((ext_vector_type(8))) short s16x8;   // 8 bf16 (4 VGPR)
typedef __attribute__((ext_vector_type(4))) float f32x4;

__device__ __forceinline__ ushort f2bf(float f) {
  unsigned u = __float_as_uint(f);
  unsigned r = (u + 0x7fffu + ((u >> 16) & 1u)) >> 16;    // RNE
  return (ushort)r;
}
__device__ __forceinline__ float bf2f(ushort h) {
  return __uint_as_float(((unsigned)h) << 16);
}
__device__ __forceinline__ float bfl(unsigned u) { return __uint_as_float(u << 16); }
__device__ __forceinline__ float bfh(unsigned u) { return __uint_as_float(u & 0xffff0000u); }

// ---------------------------------------------------------------------------
// Weight convert + transpose: fp32 [K][N] -> bf16 [N][K]
// ---------------------------------------------------------------------------
struct TD { const float* in; ushort* out; int K; int N; };
struct TPack { TD d[10]; };

__global__ __launch_bounds__(256) void k_wconv(TPack p) {
  TD t = p.d[blockIdx.y];
  int total = t.K * t.N;
  for (int i = blockIdx.x * 256 + threadIdx.x; i < total; i += gridDim.x * 256) {
    int n = i / t.K, k = i - n * t.K;
    t.out[i] = f2bf(t.in[(size_t)k * t.N + n]);
  }
}

// ---------------------------------------------------------------------------
// Build x = inputs + PE, bf16 [R][128]
// ---------------------------------------------------------------------------
__global__ __launch_bounds__(256) void k_buildx(const float* __restrict__ inp,
                                                ushort* __restrict__ x) {
  int e = blockIdx.x * 256 + threadIdx.x;          // < R*128
  int i = e & 127, r = e >> 7;
  int n = r / (WMAX * BB);
  int rem = r - n * (WMAX * BB);
  int w = rem >> 1, b = rem & 1;
  int st = n - BLK; if (st < 0) st = 0;
  float pos = (float)(st + w);
  float div = __expf(-0.0719557841f * (float)(i & 126));
  float ang = pos * div;
  float pe = (i & 1) ? __cosf(ang) : __sinf(ang);
  x[e] = f2bf(inp[(n * BB + b) * DIN + i] + pe);
}

// ---------------------------------------------------------------------------
// kp = relu(inputs @ k_W1 + k_b1) @ k_W2 + k_b2   (fp32, tiny)
// ---------------------------------------------------------------------------
__global__ __launch_bounds__(256) void k_kp(
    const float* __restrict__ inp, const float* __restrict__ kW1,
    const float* __restrict__ kb1, const float* __restrict__ kW2,
    const float* __restrict__ kb2, float* __restrict__ kp) {
  __shared__ float xs[DIN];
  __shared__ float red[8];
  int row = blockIdx.x;
  int tid = threadIdx.x;
  if (tid < DIN) xs[tid] = inp[row * DIN + tid];
  __syncthreads();
  float a0 = 0.f, a1 = 0.f;
  for (int j = tid; j < DFF; j += 256) {
    float acc = kb1[j];
    for (int k = 0; k < DIN; ++k) acc += xs[k] * kW1[k * DFF + j];
    acc = fmaxf(acc, 0.f);
    a0 += acc * kW2[2 * j];
    a1 += acc * kW2[2 * j + 1];
  }
#pragma unroll
  for (int m = 32; m > 0; m >>= 1) {
    a0 += __shfl_xor(a0, m, 64);
    a1 += __shfl_xor(a1, m, 64);
  }
  if ((tid & 63) == 0) { red[(tid >> 6) * 2] = a0; red[(tid >> 6) * 2 + 1] = a1; }
  __syncthreads();
  if (tid == 0) {
    kp[row * 2 + 0] = red[0] + red[2] + red[4] + red[6] + kb2[0];
    kp[row * 2 + 1] = red[1] + red[3] + red[5] + red[7] + kb2[1];
  }
}

// ---------------------------------------------------------------------------
// MFMA GEMM: out[M][N](bf16) = A[M][K](bf16) @ Bt[N][K](bf16)^T + bias
//            [+ resid(bf16)] [relu].  BM=128, BN=64, BK=64, 4 waves (2x2).
// ---------------------------------------------------------------------------
constexpr int BM = 128, BN = 64, BK = 64;

template<int RELU, int HAS_RES>
__global__ __launch_bounds__(256) void k_gemm(
    const ushort* __restrict__ A, const ushort* __restrict__ Bt,
    const float* __restrict__ bias, const ushort* __restrict__ resid,
    ushort* __restrict__ out, int N, int K) {
  __shared__ __align__(16) char As[BM * BK * 2];   // 16 KB, XOR-swizzled rows
  __shared__ __align__(16) char Bs[BN * BK * 2];   // 8 KB
  int tid = threadIdx.x;
  int m0 = blockIdx.x * BM, n0 = blockIdx.y * BN;
  int lane = tid & 63, w = tid >> 6;
  int wr = w >> 1, wc = w & 1;                     // wave tile: 64x32
  int fr = lane & 15, g = lane >> 4;
  f32x4 acc[4][2] = {};

  for (int kb = 0; kb < K; kb += BK) {
    __syncthreads();
#pragma unroll
    for (int it = 0; it < 4; ++it) {               // A: 128x64 bf16
      int e = tid + it * 256;
      int row = e >> 3, c = e & 7;
      uint4 v = *(const uint4*)(A + (size_t)(m0 + row) * K + kb + c * 8);
      int boff = (row * 128 + c * 16) ^ ((row & 7) << 4);
      *(uint4*)(As + boff) = v;
    }
#pragma unroll
    for (int it = 0; it < 2; ++it) {               // Bt: 64x64 bf16
      int e = tid + it * 256;
      int row = e >> 3, c = e & 7;
      uint4 v = *(const uint4*)(Bt + (size_t)(n0 + row) * K + kb + c * 8);
      int boff = (row * 128 + c * 16) ^ ((row & 7) << 4);
      *(uint4*)(Bs + boff) = v;
    }
    __syncthreads();
#pragma unroll
    for (int ks = 0; ks < 2; ++ks) {
      int kByte = ks * 64 + g * 16;
      s16x8 a[4], b[2];
#pragma unroll
      for (int m = 0; m < 4; ++m) {
        int row = wr * 64 + m * 16 + fr;
        a[m] = *(const s16x8*)(As + ((row * 128 + kByte) ^ ((row & 7) << 4)));
      }
#pragma unroll
      for (int n = 0; n < 2; ++n) {
        int row = wc * 32 + n * 16 + fr;
        b[n] = *(const s16x8*)(Bs + ((row * 128 + kByte) ^ ((row & 7) << 4)));
      }
#pragma unroll
      for (int m = 0; m < 4; ++m)
#pragma unroll
        for (int n = 0; n < 2; ++n)
          acc[m][n] = __builtin_amdgcn_mfma_f32_16x16x32_bf16(a[m], b[n], acc[m][n], 0, 0, 0);
    }
  }
  // epilogue: C row = g*4+j, col = fr (verified gfx950 C/D layout)
#pragma unroll
  for (int m = 0; m < 4; ++m) {
    int row = m0 + wr * 64 + m * 16 + g * 4;
#pragma unroll
    for (int n = 0; n < 2; ++n) {
      int col = n0 + wc * 32 + n * 16 + fr;
      float bv = bias[col];
#pragma unroll
      for (int j = 0; j < 4; ++j) {
        float v = acc[m][n][j] + bv;
        if (HAS_RES) v += bf2f(resid[(size_t)(row + j) * N + col]);
        if (RELU) v = fmaxf(v, 0.f);
        out[(size_t)(row + j) * N + col] = f2bf(v);
      }
    }
  }
}

// ---------------------------------------------------------------------------
// Windowed attention per (n,b,head). qkv bf16 in, o bf16 out. fp32 math.
// ---------------------------------------------------------------------------
__global__ __launch_bounds__(128) void k_attn(
    const ushort* __restrict__ qkv, ushort* __restrict__ o,
    const int* __restrict__ lenp) {
  int L = lenp[0];
  int blk = blockIdx.x;
  int hh = blk & 7;
  int nb = blk >> 3;
  int b = nb & 1;
  int n = nb >> 1;
  int s0 = n - BLK; if (s0 < 0) s0 = 0;
  int e0 = n + BLK + 1; if (e0 > L) e0 = L;
  int vn = e0 - s0;
  __shared__ float kt[WMAX][DH];
  __shared__ float vt[WMAX][DH];
  int tid = threadIdx.x;
  for (int e = tid; e < WMAX * 16; e += 128) {
    int wrow = e >> 4, dp = e & 15;
    const ushort* rp = qkv + (size_t)((n * WMAX + wrow) * BB + b) * (3 * DD);
    unsigned kk = *(const unsigned*)(rp + DD + hh * DH + dp * 2);
    kt[wrow][dp * 2]     = bfl(kk);
    kt[wrow][dp * 2 + 1] = bfh(kk);
    unsigned vv = *(const unsigned*)(rp + 2 * DD + hh * DH + dp * 2);
    vt[wrow][dp * 2]     = bfl(vv);
    vt[wrow][dp * 2 + 1] = bfh(vv);
  }
  __syncthreads();
  int q = tid;
  if (q < WMAX) {
    const ushort* qp = qkv + (size_t)((n * WMAX + q) * BB + b) * (3 * DD) + hh * DH;
    float qf[32];
    const uint4* qp4 = (const uint4*)qp;
#pragma unroll
    for (int u4 = 0; u4 < 4; ++u4) {
      uint4 qq = qp4[u4];
      qf[u4 * 8 + 0] = bfl(qq.x); qf[u4 * 8 + 1] = bfh(qq.x);
      qf[u4 * 8 + 2] = bfl(qq.y); qf[u4 * 8 + 3] = bfh(qq.y);
      qf[u4 * 8 + 4] = bfl(qq.z); qf[u4 * 8 + 5] = bfh(qq.z);
      qf[u4 * 8 + 6] = bfl(qq.w); qf[u4 * 8 + 7] = bfh(qq.w);
    }
    float s[WMAX];
    float mx = -3e38f;
#pragma unroll
    for (int j = 0; j < WMAX; ++j) {
      float acc = 0.f;
      const float* kr = kt[j];
#pragma unroll
      for (int d = 0; d < 32; ++d) acc += qf[d] * kr[d];
      acc *= 0.17677669529663687f;
      s[j] = acc;
      mx = (j < vn) ? fmaxf(mx, acc) : mx;
    }
    float sum = 0.f;
#pragma unroll
    for (int j = 0; j < WMAX; ++j) {
      float p = (j < vn) ? __expf(s[j] - mx) : 0.f;
      s[j] = p;
      sum += p;
    }
    float inv = 1.f / sum;
    float ov[32];
#pragma unroll
    for (int d = 0; d < 32; ++d) ov[d] = 0.f;
#pragma unroll
    for (int j = 0; j < WMAX; ++j) {
      float p = s[j];
      const float* vr = vt[j];
#pragma unroll
      for (int d = 0; d < 32; ++d) ov[d] += p * vr[d];
    }
    ushort* op = o + (size_t)((n * WMAX + q) * BB + b) * DD + hh * DH;
#pragma unroll
    for (int dp = 0; dp < 16; ++dp) {
      unsigned lo = f2bf(ov[2 * dp] * inv);
      unsigned hi = f2bf(ov[2 * dp + 1] * inv);
      *(unsigned*)(op + 2 * dp) = lo | (hi << 16);
    }
  }
}

// ---------------------------------------------------------------------------
// LayerNorm: z bf16 [R][256] -> h bf16 [R][256].  One row per wave.
// ---------------------------------------------------------------------------
__global__ __launch_bounds__(256) void k_ln(
    const ushort* __restrict__ z, const float* __restrict__ g,
    const float* __restrict__ be, ushort* __restrict__ h) {
  int row = blockIdx.x * 4 + (threadIdx.x >> 6);
  int lane = threadIdx.x & 63;
  const ushort* zr = z + (size_t)row * DD + lane * 4;
  uint2 pk = *(const uint2*)zr;
  float v0 = bfl(pk.x), v1 = bfh(pk.x), v2 = bfl(pk.y), v3 = bfh(pk.y);
  float sm = v0 + v1 + v2 + v3;
  float sq = v0 * v0 + v1 * v1 + v2 * v2 + v3 * v3;
#pragma unroll
  for (int m = 32; m > 0; m >>= 1) {
    sm += __shfl_xor(sm, m, 64);
    sq += __shfl_xor(sq, m, 64);
  }
  float mean = sm * (1.f / DD);
  float var = sq * (1.f / DD) - mean * mean;
  float rs = rsqrtf(var + 1e-5f);
  int c = lane * 4;
  float o0 = (v0 - mean) * rs * g[c] + be[c];
  float o1 = (v1 - mean) * rs * g[c + 1] + be[c + 1];
  float o2 = (v2 - mean) * rs * g[c + 2] + be[c + 2];
  float o3 = (v3 - mean) * rs * g[c + 3] + be[c + 3];
  uint2 outp;
  outp.x = (unsigned)f2bf(o0) | ((unsigned)f2bf(o1) << 16);
  outp.y = (unsigned)f2bf(o2) | ((unsigned)f2bf(o3) << 16);
  *(uint2*)(h + (size_t)row * DD + c) = outp;
}

// ---------------------------------------------------------------------------
// Final hierarchical softmax-gather (h bf16)
// ---------------------------------------------------------------------------
__global__ __launch_bounds__(256) void k_final(
    const ushort* __restrict__ h, const float* __restrict__ kp,
    float* __restrict__ out, const int* __restrict__ lenp) {
  int L = lenp[0];
  int t = blockIdx.x >> 1, b = blockIdx.x & 1;
  float hsc = (float)L / (float)NN;
  int nlo = t - BLK; if (nlo < 0) nlo = 0;
  int nhi = t + BLK; if (nhi > NN - 1) nhi = NN - 1;
  float mx = -3e38f;
  for (int n = nlo; n <= nhi; ++n) {
    float kp0 = kp[(n * BB + b) * 2 + 0];
    float kp1 = kp[(n * BB + b) * 2 + 1];
    float dif = (float)t - (float)n * hsc - kp0;
    float lg = -dif * dif * __expf(kp1);
    mx = fmaxf(mx, lg);
  }
  float sum = 0.f, acc = 0.f;
  int c = threadIdx.x;
  for (int n = nlo; n <= nhi; ++n) {
    float kp0 = kp[(n * BB + b) * 2 + 0];
    float kp1 = kp[(n * BB + b) * 2 + 1];
    float dif = (float)t - (float)n * hsc - kp0;
    float lg = -dif * dif * __expf(kp1);
    float p = __expf(lg - mx);
    sum += p;
    int st = n - BLK; if (st < 0) st = 0;
    int w = t - st;
    acc += p * bf2f(h[(size_t)((n * WMAX + w) * BB + b) * DD + c]);
  }
  out[(size_t)(t * BB + b) * DD + c] = acc / sum;
}

// ---------------------------------------------------------------------------
extern "C" void kernel_launch(void* const* d_in, const int* in_sizes, int n_in,
                              void* d_out, int out_size, void* d_ws, size_t ws_size,
                              hipStream_t stream) {
  const float* inputs = (const float*)d_in[0];
  const float* in_W1  = (const float*)d_in[1];
  const float* in_b1  = (const float*)d_in[2];
  const float* in_W2  = (const float*)d_in[3];
  const float* in_b2  = (const float*)d_in[4];
  const float* k_W1   = (const float*)d_in[5];
  const float* k_b1   = (const float*)d_in[6];
  const float* k_W2   = (const float*)d_in[7];
  const float* k_b2   = (const float*)d_in[8];
  const float* Wqkv   = (const float*)d_in[9];
  const float* bqkv   = (const float*)d_in[10];
  const float* Wo     = (const float*)d_in[11];
  const float* bo     = (const float*)d_in[12];
  const float* ln1_g  = (const float*)d_in[13];
  const float* ln1_b  = (const float*)d_in[14];
  const float* W1     = (const float*)d_in[15];
  const float* b1     = (const float*)d_in[16];
  const float* W2     = (const float*)d_in[17];
  const float* b2     = (const float*)d_in[18];
  const float* ln2_g  = (const float*)d_in[19];
  const float* ln2_b  = (const float*)d_in[20];
  const int*   lenp   = (const int*)d_in[21];
  float* out = (float*)d_out;
  (void)in_sizes; (void)n_in; (void)ws_size;

  // --- workspace layout (bf16 units) ---
  ushort* wsu = (ushort*)d_ws;
  size_t off = 0;
  auto alloc = [&](size_t nelem) { ushort* p = wsu + off; off += (nelem + 7) & ~7ull; return p; };
  ushort* inW1t = alloc((size_t)DFF * DIN);          // 1024x128
  ushort* inW2t = alloc((size_t)DD * DFF);           // 256x1024
  ushort* Wqkvt = alloc((size_t)NL * 3 * DD * DD);   // 2 x 768x256
  ushort* Wot   = alloc((size_t)NL * DD * DD);       // 2 x 256x256
  ushort* W1t   = alloc((size_t)NL * DFF * DD);      // 2 x 1024x256
  ushort* W2t   = alloc((size_t)NL * DD * DFF);      // 2 x 256x1024
  ushort* xz    = alloc((size_t)RROWS * DD);         // x (R*128) / z (R*256) shared
  ushort* tq    = alloc((size_t)RROWS * DFF);        // t / qkv shared
  ushort* hb    = alloc((size_t)RROWS * DD);
  ushort* ob    = alloc((size_t)RROWS * DD);
  float*  kp    = (float*)(wsu + off);               // 512 f32

  int L = out_size / (BB * DD);                      // 160

  // weight convert+transpose (10 matrices in one kernel)
  TPack tp;
  tp.d[0] = {in_W1, inW1t, DIN, DFF};
  tp.d[1] = {in_W2, inW2t, DFF, DD};
  tp.d[2] = {Wqkv,                       Wqkvt,                     DD, 3 * DD};
  tp.d[3] = {Wqkv + (size_t)DD * 3 * DD, Wqkvt + (size_t)3 * DD * DD, DD, 3 * DD};
  tp.d[4] = {Wo,                    Wot,                  DD, DD};
  tp.d[5] = {Wo + (size_t)DD * DD,  Wot + (size_t)DD * DD, DD, DD};
  tp.d[6] = {W1,                     W1t,                   DD, DFF};
  tp.d[7] = {W1 + (size_t)DD * DFF,  W1t + (size_t)DFF * DD, DD, DFF};
  tp.d[8] = {W2,                     W2t,                   DFF, DD};
  tp.d[9] = {W2 + (size_t)DFF * DD,  W2t + (size_t)DD * DFF, DFF, DD};
  k_wconv<<<dim3(1024, 10), 256, 0, stream>>>(tp);

  k_buildx<<<RROWS * DIN / 256, 256, 0, stream>>>(inputs, xz);
  k_kp<<<NN * BB, 256, 0, stream>>>(inputs, k_W1, k_b1, k_W2, k_b2, kp);

  // input MLP
  k_gemm<1, 0><<<dim3(RROWS / BM, DFF / BN), 256, 0, stream>>>(
      xz, inW1t, in_b1, nullptr, tq, DFF, DIN);
  k_gemm<0, 0><<<dim3(RROWS / BM, DD / BN), 256, 0, stream>>>(
      tq, inW2t, in_b2, nullptr, hb, DD, DFF);

  for (int l = 0; l < NL; ++l) {
    k_gemm<0, 0><<<dim3(RROWS / BM, 3 * DD / BN), 256, 0, stream>>>(
        hb, Wqkvt + (size_t)l * 3 * DD * DD, bqkv + (size_t)l * 3 * DD,
        nullptr, tq, 3 * DD, DD);
    k_attn<<<NN * BB * NH, 128, 0, stream>>>(tq, ob, lenp);
    k_gemm<0, 1><<<dim3(RROWS / BM, DD / BN), 256, 0, stream>>>(
        ob, Wot + (size_t)l * DD * DD, bo + (size_t)l * DD, hb, xz, DD, DD);
    k_ln<<<RROWS / 4, 256, 0, stream>>>(xz, ln1_g + (size_t)l * DD,
                                        ln1_b + (size_t)l * DD, hb);
    k_gemm<1, 0><<<dim3(RROWS / BM, DFF / BN), 256, 0, stream>>>(
        hb, W1t + (size_t)l * DFF * DD, b1 + (size_t)l * DFF, nullptr, tq, DFF, DD);
    k_gemm<0, 1><<<dim3(RROWS / BM, DD / BN), 256, 0, stream>>>(
        tq, W2t + (size_t)l * DD * DFF, b2 + (size_t)l * DD, hb, xz, DD, DFF);
    k_ln<<<RROWS / 4, 256, 0, stream>>>(xz, ln2_g + (size_t)l * DD,
                                        ln2_b + (size_t)l * DD, hb);
  }
  k_final<<<L * BB, 256, 0, stream>>>(hb, kp, out, lenp);
}

// Round 3
// 323.723 us; speedup vs baseline: 6.2869x; 1.3764x over previous
//
#include <hip/hip_runtime.h>

constexpr int NN    = 128;
constexpr int BB    = 2;
constexpr int DIN   = 128;
constexpr int DD    = 256;
constexpr int DFF   = 1024;
constexpr int NH    = 8;
constexpr int DH    = 32;
constexpr int NL    = 2;
constexpr int BLK   = 32;
constexpr int WMAX  = 2 * BLK + 1;       // 65
constexpr int RROWS = NN * WMAX * BB;    // 16640

typedef __attribute__((ext_vector_type(8))) short s16x8;   // 8 bf16 (4 VGPR)
typedef __attribute__((ext_vector_type(4))) float f32x4;

__device__ __forceinline__ ushort f2bf(float f) {
  unsigned u = __float_as_uint(f);
  unsigned r = (u + 0x7fffu + ((u >> 16) & 1u)) >> 16;    // RNE
  return (ushort)r;
}
__device__ __forceinline__ float bf2f(ushort h) {
  return __uint_as_float(((unsigned)h) << 16);
}
__device__ __forceinline__ float bfl(unsigned u) { return __uint_as_float(u << 16); }
__device__ __forceinline__ float bfh(unsigned u) { return __uint_as_float(u & 0xffff0000u); }

// ---------------------------------------------------------------------------
// Weight convert + transpose: fp32 [K][N] -> bf16 [N][K]
// ---------------------------------------------------------------------------
struct TD { const float* in; ushort* out; int K; int N; };
struct TPack { TD d[10]; };

__global__ __launch_bounds__(256) void k_wconv(TPack p) {
  TD t = p.d[blockIdx.y];
  int total = t.K * t.N;
  for (int i = blockIdx.x * 256 + threadIdx.x; i < total; i += gridDim.x * 256) {
    int n = i / t.K, k = i - n * t.K;
    t.out[i] = f2bf(t.in[(size_t)k * t.N + n]);
  }
}

// ---------------------------------------------------------------------------
// Build x = inputs + PE, bf16 [R][128]
// ---------------------------------------------------------------------------
__global__ __launch_bounds__(256) void k_buildx(const float* __restrict__ inp,
                                                ushort* __restrict__ x) {
  int e = blockIdx.x * 256 + threadIdx.x;          // < R*128
  int i = e & 127, r = e >> 7;
  int n = r / (WMAX * BB);
  int rem = r - n * (WMAX * BB);
  int w = rem >> 1, b = rem & 1;
  int st = n - BLK; if (st < 0) st = 0;
  float pos = (float)(st + w);
  float div = __expf(-0.0719557841f * (float)(i & 126));
  float ang = pos * div;
  float pe = (i & 1) ? __cosf(ang) : __sinf(ang);
  x[e] = f2bf(inp[(n * BB + b) * DIN + i] + pe);
}

// ---------------------------------------------------------------------------
// kp = relu(inputs @ k_W1 + k_b1) @ k_W2 + k_b2   (fp32, tiny)
// ---------------------------------------------------------------------------
__global__ __launch_bounds__(256) void k_kp(
    const float* __restrict__ inp, const float* __restrict__ kW1,
    const float* __restrict__ kb1, const float* __restrict__ kW2,
    const float* __restrict__ kb2, float* __restrict__ kp) {
  __shared__ float xs[DIN];
  __shared__ float red[8];
  int row = blockIdx.x;
  int tid = threadIdx.x;
  if (tid < DIN) xs[tid] = inp[row * DIN + tid];
  __syncthreads();
  float a0 = 0.f, a1 = 0.f;
  for (int j = tid; j < DFF; j += 256) {
    float acc = kb1[j];
    for (int k = 0; k < DIN; ++k) acc += xs[k] * kW1[k * DFF + j];
    acc = fmaxf(acc, 0.f);
    a0 += acc * kW2[2 * j];
    a1 += acc * kW2[2 * j + 1];
  }
#pragma unroll
  for (int m = 32; m > 0; m >>= 1) {
    a0 += __shfl_xor(a0, m, 64);
    a1 += __shfl_xor(a1, m, 64);
  }
  if ((tid & 63) == 0) { red[(tid >> 6) * 2] = a0; red[(tid >> 6) * 2 + 1] = a1; }
  __syncthreads();
  if (tid == 0) {
    kp[row * 2 + 0] = red[0] + red[2] + red[4] + red[6] + kb2[0];
    kp[row * 2 + 1] = red[1] + red[3] + red[5] + red[7] + kb2[1];
  }
}

// ---------------------------------------------------------------------------
// MFMA GEMM: out[M][N](bf16) = A[M][K](bf16) @ Bt[N][K](bf16)^T + bias
//            [+ resid(bf16)] [relu].  BM=128, BN=64, BK=64, 4 waves (2x2).
// ---------------------------------------------------------------------------
constexpr int BM = 128, BN = 64, BK = 64;

template<int RELU, int HAS_RES>
__global__ __launch_bounds__(256) void k_gemm(
    const ushort* __restrict__ A, const ushort* __restrict__ Bt,
    const float* __restrict__ bias, const ushort* __restrict__ resid,
    ushort* __restrict__ out, int N, int K) {
  __shared__ __align__(16) char As[BM * BK * 2];   // 16 KB, XOR-swizzled rows
  __shared__ __align__(16) char Bs[BN * BK * 2];   // 8 KB
  int tid = threadIdx.x;
  int m0 = blockIdx.x * BM, n0 = blockIdx.y * BN;
  int lane = tid & 63, w = tid >> 6;
  int wr = w >> 1, wc = w & 1;                     // wave tile: 64x32
  int fr = lane & 15, g = lane >> 4;
  f32x4 acc[4][2] = {};

  for (int kb = 0; kb < K; kb += BK) {
    __syncthreads();
#pragma unroll
    for (int it = 0; it < 4; ++it) {               // A: 128x64 bf16
      int e = tid + it * 256;
      int row = e >> 3, c = e & 7;
      uint4 v = *(const uint4*)(A + (size_t)(m0 + row) * K + kb + c * 8);
      int boff = (row * 128 + c * 16) ^ ((row & 7) << 4);
      *(uint4*)(As + boff) = v;
    }
#pragma unroll
    for (int it = 0; it < 2; ++it) {               // Bt: 64x64 bf16
      int e = tid + it * 256;
      int row = e >> 3, c = e & 7;
      uint4 v = *(const uint4*)(Bt + (size_t)(n0 + row) * K + kb + c * 8);
      int boff = (row * 128 + c * 16) ^ ((row & 7) << 4);
      *(uint4*)(Bs + boff) = v;
    }
    __syncthreads();
#pragma unroll
    for (int ks = 0; ks < 2; ++ks) {
      int kByte = ks * 64 + g * 16;
      s16x8 a[4], b[2];
#pragma unroll
      for (int m = 0; m < 4; ++m) {
        int row = wr * 64 + m * 16 + fr;
        a[m] = *(const s16x8*)(As + ((row * 128 + kByte) ^ ((row & 7) << 4)));
      }
#pragma unroll
      for (int n = 0; n < 2; ++n) {
        int row = wc * 32 + n * 16 + fr;
        b[n] = *(const s16x8*)(Bs + ((row * 128 + kByte) ^ ((row & 7) << 4)));
      }
#pragma unroll
      for (int m = 0; m < 4; ++m)
#pragma unroll
        for (int n = 0; n < 2; ++n)
          acc[m][n] = __builtin_amdgcn_mfma_f32_16x16x32_bf16(a[m], b[n], acc[m][n], 0, 0, 0);
    }
  }
  // epilogue: C row = g*4+j, col = fr (verified gfx950 C/D layout)
#pragma unroll
  for (int m = 0; m < 4; ++m) {
    int row = m0 + wr * 64 + m * 16 + g * 4;
#pragma unroll
    for (int n = 0; n < 2; ++n) {
      int col = n0 + wc * 32 + n * 16 + fr;
      float bv = bias[col];
#pragma unroll
      for (int j = 0; j < 4; ++j) {
        float v = acc[m][n][j] + bv;
        if (HAS_RES) v += bf2f(resid[(size_t)(row + j) * N + col]);
        if (RELU) v = fmaxf(v, 0.f);
        out[(size_t)(row + j) * N + col] = f2bf(v);
      }
    }
  }
}

// ---------------------------------------------------------------------------
// MFMA windowed attention. One block per (n,b,head), 5 waves.
// Wave w owns q-rows 16w..16w+15 (80 rows, 65 valid).
// ---------------------------------------------------------------------------
constexpr int QKS = 40;    // Q/K LDS row stride (ushorts)
constexpr int VTS = 104;   // Vt LDS row stride
constexpr int PS  = 104;   // P  LDS row stride

__global__ __launch_bounds__(320) void k_attn(
    const ushort* __restrict__ qkv, ushort* __restrict__ o,
    const int* __restrict__ lenp) {
  __shared__ __align__(16) ushort Qs[80 * QKS];     // 6.4 KB
  __shared__ __align__(16) ushort Ks[80 * QKS];     // 6.4 KB
  __shared__ __align__(16) ushort Vt[32 * VTS];     // 6.7 KB (transposed V)
  __shared__ __align__(16) ushort Pb[5 * 16 * PS];  // 16.6 KB
  int L = lenp[0];
  int blk = blockIdx.x;
  int hh = blk & 7;
  int nb = blk >> 3;
  int b = nb & 1;
  int n = nb >> 1;
  int s0 = n - BLK; if (s0 < 0) s0 = 0;
  int e0 = n + BLK + 1; if (e0 > L) e0 = L;
  int vn = e0 - s0;
  int tid = threadIdx.x;

  // zero pads: Q/K rows 65..79, Vt fully
  for (int i = tid; i < 32 * VTS / 2; i += 320) ((uint*)Vt)[i] = 0;
  for (int i = tid; i < 15 * QKS / 2; i += 320) {
    ((uint*)(Qs + 65 * QKS))[i] = 0;
    ((uint*)(Ks + 65 * QKS))[i] = 0;
  }
  // stage Q, K, V (V transposed)
  for (int e = tid; e < 65 * 4; e += 320) {
    int r = e >> 2, c = e & 3;
    const ushort* base = qkv + ((size_t)(n * WMAX + r) * BB + b) * (3 * DD) + hh * DH;
    *(uint4*)(Qs + r * QKS + c * 8) = *(const uint4*)(base + c * 8);
    *(uint4*)(Ks + r * QKS + c * 8) = *(const uint4*)(base + DD + c * 8);
    uint4 vv = *(const uint4*)(base + 2 * DD + c * 8);
    const ushort* vp = (const ushort*)&vv;
#pragma unroll
    for (int u = 0; u < 8; ++u) Vt[(c * 8 + u) * VTS + r] = vp[u];
  }
  __syncthreads();

  int w = tid >> 6, lane = tid & 63;
  int fr = lane & 15, g = lane >> 4;
  int q0 = w * 16;
  ushort* Pw = Pb + w * 16 * PS;

  // QK^T: 5 col tiles, K=32 (=DH) in one MFMA each
  s16x8 aq = *(const s16x8*)(Qs + (q0 + fr) * QKS + g * 8);
  f32x4 sacc[5];
#pragma unroll
  for (int t = 0; t < 5; ++t) {
    s16x8 bk = *(const s16x8*)(Ks + (t * 16 + fr) * QKS + g * 8);
    f32x4 z = {0.f, 0.f, 0.f, 0.f};
    sacc[t] = __builtin_amdgcn_mfma_f32_16x16x32_bf16(aq, bk, z, 0, 0, 0);
  }
  // softmax per row (row = g*4+j, col = t*16+fr). Row-reduce across 16 lanes.
  const float scl = 0.17677669529663687f;
#pragma unroll
  for (int j = 0; j < 4; ++j) {
    float pv[5];
    float mx = -3e38f;
#pragma unroll
    for (int t = 0; t < 5; ++t) {
      bool ok = (t * 16 + fr) < vn;
      pv[t] = ok ? sacc[t][j] * scl : -3e38f;
      mx = fmaxf(mx, pv[t]);
    }
#pragma unroll
    for (int d = 1; d < 16; d <<= 1) mx = fmaxf(mx, __shfl_xor(mx, d, 64));
    float sum = 0.f;
#pragma unroll
    for (int t = 0; t < 5; ++t) {
      float e = ((t * 16 + fr) < vn) ? __expf(pv[t] - mx) : 0.f;
      pv[t] = e;
      sum += e;
    }
#pragma unroll
    for (int d = 1; d < 16; d <<= 1) sum += __shfl_xor(sum, d, 64);
    float inv = 1.f / sum;
#pragma unroll
    for (int t = 0; t < 5; ++t)
      Pw[(g * 4 + j) * PS + t * 16 + fr] = f2bf(pv[t] * inv);
  }
  // zero P cols 80..95 (read by the k0=64 PV step)
  {
    int zr = lane >> 2, zc = 80 + (lane & 3) * 4;
    *(uint2*)(Pw + zr * PS + zc) = make_uint2(0u, 0u);
  }
  __syncthreads();

  // PV: O[16x32] = P[16x96] @ V[96x32], 3 k-steps x 2 n-tiles
  f32x4 oacc[2] = {};
#pragma unroll
  for (int k0 = 0; k0 < 3; ++k0) {
    s16x8 ap = *(const s16x8*)(Pw + fr * PS + k0 * 32 + g * 8);
#pragma unroll
    for (int nt = 0; nt < 2; ++nt) {
      s16x8 bv = *(const s16x8*)(Vt + (nt * 16 + fr) * VTS + k0 * 32 + g * 8);
      oacc[nt] = __builtin_amdgcn_mfma_f32_16x16x32_bf16(ap, bv, oacc[nt], 0, 0, 0);
    }
  }
  // store valid rows
#pragma unroll
  for (int nt = 0; nt < 2; ++nt) {
#pragma unroll
    for (int j = 0; j < 4; ++j) {
      int qr = q0 + g * 4 + j;
      if (qr < WMAX)
        o[((size_t)(n * WMAX + qr) * BB + b) * DD + hh * DH + nt * 16 + fr] =
            f2bf(oacc[nt][j]);
    }
  }
}

// ---------------------------------------------------------------------------
// LayerNorm: z bf16 [R][256] -> h bf16 [R][256].  One row per wave.
// ---------------------------------------------------------------------------
__global__ __launch_bounds__(256) void k_ln(
    const ushort* __restrict__ z, const float* __restrict__ g,
    const float* __restrict__ be, ushort* __restrict__ h) {
  int row = blockIdx.x * 4 + (threadIdx.x >> 6);
  int lane = threadIdx.x & 63;
  const ushort* zr = z + (size_t)row * DD + lane * 4;
  uint2 pk = *(const uint2*)zr;
  float v0 = bfl(pk.x), v1 = bfh(pk.x), v2 = bfl(pk.y), v3 = bfh(pk.y);
  float sm = v0 + v1 + v2 + v3;
  float sq = v0 * v0 + v1 * v1 + v2 * v2 + v3 * v3;
#pragma unroll
  for (int m = 32; m > 0; m >>= 1) {
    sm += __shfl_xor(sm, m, 64);
    sq += __shfl_xor(sq, m, 64);
  }
  float mean = sm * (1.f / DD);
  float var = sq * (1.f / DD) - mean * mean;
  float rs = rsqrtf(var + 1e-5f);
  int c = lane * 4;
  float o0 = (v0 - mean) * rs * g[c] + be[c];
  float o1 = (v1 - mean) * rs * g[c + 1] + be[c + 1];
  float o2 = (v2 - mean) * rs * g[c + 2] + be[c + 2];
  float o3 = (v3 - mean) * rs * g[c + 3] + be[c + 3];
  uint2 outp;
  outp.x = (unsigned)f2bf(o0) | ((unsigned)f2bf(o1) << 16);
  outp.y = (unsigned)f2bf(o2) | ((unsigned)f2bf(o3) << 16);
  *(uint2*)(h + (size_t)row * DD + c) = outp;
}

// ---------------------------------------------------------------------------
// Final hierarchical softmax-gather (h bf16)
// ---------------------------------------------------------------------------
__global__ __launch_bounds__(256) void k_final(
    const ushort* __restrict__ h, const float* __restrict__ kp,
    float* __restrict__ out, const int* __restrict__ lenp) {
  int L = lenp[0];
  int t = blockIdx.x >> 1, b = blockIdx.x & 1;
  float hsc = (float)L / (float)NN;
  int nlo = t - BLK; if (nlo < 0) nlo = 0;
  int nhi = t + BLK; if (nhi > NN - 1) nhi = NN - 1;
  float mx = -3e38f;
  for (int n = nlo; n <= nhi; ++n) {
    float kp0 = kp[(n * BB + b) * 2 + 0];
    float kp1 = kp[(n * BB + b) * 2 + 1];
    float dif = (float)t - (float)n * hsc - kp0;
    float lg = -dif * dif * __expf(kp1);
    mx = fmaxf(mx, lg);
  }
  float sum = 0.f, acc = 0.f;
  int c = threadIdx.x;
  for (int n = nlo; n <= nhi; ++n) {
    float kp0 = kp[(n * BB + b) * 2 + 0];
    float kp1 = kp[(n * BB + b) * 2 + 1];
    float dif = (float)t - (float)n * hsc - kp0;
    float lg = -dif * dif * __expf(kp1);
    float p = __expf(lg - mx);
    sum += p;
    int st = n - BLK; if (st < 0) st = 0;
    int w = t - st;
    acc += p * bf2f(h[(size_t)((n * WMAX + w) * BB + b) * DD + c]);
  }
  out[(size_t)(t * BB + b) * DD + c] = acc / sum;
}

// ---------------------------------------------------------------------------
extern "C" void kernel_launch(void* const* d_in, const int* in_sizes, int n_in,
                              void* d_out, int out_size, void* d_ws, size_t ws_size,
                              hipStream_t stream) {
  const float* inputs = (const float*)d_in[0];
  const float* in_W1  = (const float*)d_in[1];
  const float* in_b1  = (const float*)d_in[2];
  const float* in_W2  = (const float*)d_in[3];
  const float* in_b2  = (const float*)d_in[4];
  const float* k_W1   = (const float*)d_in[5];
  const float* k_b1   = (const float*)d_in[6];
  const float* k_W2   = (const float*)d_in[7];
  const float* k_b2   = (const float*)d_in[8];
  const float* Wqkv   = (const float*)d_in[9];
  const float* bqkv   = (const float*)d_in[10];
  const float* Wo     = (const float*)d_in[11];
  const float* bo     = (const float*)d_in[12];
  const float* ln1_g  = (const float*)d_in[13];
  const float* ln1_b  = (const float*)d_in[14];
  const float* W1     = (const float*)d_in[15];
  const float* b1     = (const float*)d_in[16];
  const float* W2     = (const float*)d_in[17];
  const float* b2     = (const float*)d_in[18];
  const float* ln2_g  = (const float*)d_in[19];
  const float* ln2_b  = (const float*)d_in[20];
  const int*   lenp   = (const int*)d_in[21];
  float* out = (float*)d_out;
  (void)in_sizes; (void)n_in; (void)ws_size;

  // --- workspace layout (bf16 units) ---
  ushort* wsu = (ushort*)d_ws;
  size_t off = 0;
  auto alloc = [&](size_t nelem) { ushort* p = wsu + off; off += (nelem + 7) & ~7ull; return p; };
  ushort* inW1t = alloc((size_t)DFF * DIN);          // 1024x128
  ushort* inW2t = alloc((size_t)DD * DFF);           // 256x1024
  ushort* Wqkvt = alloc((size_t)NL * 3 * DD * DD);   // 2 x 768x256
  ushort* Wot   = alloc((size_t)NL * DD * DD);       // 2 x 256x256
  ushort* W1t   = alloc((size_t)NL * DFF * DD);      // 2 x 1024x256
  ushort* W2t   = alloc((size_t)NL * DD * DFF);      // 2 x 256x1024
  ushort* xz    = alloc((size_t)RROWS * DD);         // x (R*128) / z (R*256) shared
  ushort* tq    = alloc((size_t)RROWS * DFF);        // t / qkv shared
  ushort* hb    = alloc((size_t)RROWS * DD);
  ushort* ob    = alloc((size_t)RROWS * DD);
  float*  kp    = (float*)(wsu + off);               // 512 f32

  int L = out_size / (BB * DD);                      // 160

  // weight convert+transpose (10 matrices in one kernel)
  TPack tp;
  tp.d[0] = {in_W1, inW1t, DIN, DFF};
  tp.d[1] = {in_W2, inW2t, DFF, DD};
  tp.d[2] = {Wqkv,                       Wqkvt,                     DD, 3 * DD};
  tp.d[3] = {Wqkv + (size_t)DD * 3 * DD, Wqkvt + (size_t)3 * DD * DD, DD, 3 * DD};
  tp.d[4] = {Wo,                    Wot,                  DD, DD};
  tp.d[5] = {Wo + (size_t)DD * DD,  Wot + (size_t)DD * DD, DD, DD};
  tp.d[6] = {W1,                     W1t,                   DD, DFF};
  tp.d[7] = {W1 + (size_t)DD * DFF,  W1t + (size_t)DFF * DD, DD, DFF};
  tp.d[8] = {W2,                     W2t,                   DFF, DD};
  tp.d[9] = {W2 + (size_t)DFF * DD,  W2t + (size_t)DD * DFF, DFF, DD};
  k_wconv<<<dim3(1024, 10), 256, 0, stream>>>(tp);

  k_buildx<<<RROWS * DIN / 256, 256, 0, stream>>>(inputs, xz);
  k_kp<<<NN * BB, 256, 0, stream>>>(inputs, k_W1, k_b1, k_W2, k_b2, kp);

  // input MLP
  k_gemm<1, 0><<<dim3(RROWS / BM, DFF / BN), 256, 0, stream>>>(
      xz, inW1t, in_b1, nullptr, tq, DFF, DIN);
  k_gemm<0, 0><<<dim3(RROWS / BM, DD / BN), 256, 0, stream>>>(
      tq, inW2t, in_b2, nullptr, hb, DD, DFF);

  for (int l = 0; l < NL; ++l) {
    k_gemm<0, 0><<<dim3(RROWS / BM, 3 * DD / BN), 256, 0, stream>>>(
        hb, Wqkvt + (size_t)l * 3 * DD * DD, bqkv + (size_t)l * 3 * DD,
        nullptr, tq, 3 * DD, DD);
    k_attn<<<NN * BB * NH, 320, 0, stream>>>(tq, ob, lenp);
    k_gemm<0, 1><<<dim3(RROWS / BM, DD / BN), 256, 0, stream>>>(
        ob, Wot + (size_t)l * DD * DD, bo + (size_t)l * DD, hb, xz, DD, DD);
    k_ln<<<RROWS / 4, 256, 0, stream>>>(xz, ln1_g + (size_t)l * DD,
                                        ln1_b + (size_t)l * DD, hb);
    k_gemm<1, 0><<<dim3(RROWS / BM, DFF / BN), 256, 0, stream>>>(
        hb, W1t + (size_t)l * DFF * DD, b1 + (size_t)l * DFF, nullptr, tq, DFF, DD);
    k_gemm<0, 1><<<dim3(RROWS / BM, DD / BN), 256, 0, stream>>>(
        tq, W2t + (size_t)l * DD * DFF, b2 + (size_t)l * DD, hb, xz, DD, DFF);
    k_ln<<<RROWS / 4, 256, 0, stream>>>(xz, ln2_g + (size_t)l * DD,
                                        ln2_b + (size_t)l * DD, hb);
  }
  k_final<<<L * BB, 256, 0, stream>>>(hb, kp, out, lenp);
}

// Round 4
// 296.572 us; speedup vs baseline: 6.8624x; 1.0916x over previous
//
#include <hip/hip_runtime.h>

constexpr int NN    = 128;
constexpr int BB    = 2;
constexpr int DIN   = 128;
constexpr int DD    = 256;
constexpr int DFF   = 1024;
constexpr int NH    = 8;
constexpr int DH    = 32;
constexpr int NL    = 2;
constexpr int BLK   = 32;
constexpr int WMAX  = 2 * BLK + 1;       // 65
constexpr int RROWS = NN * WMAX * BB;    // 16640

typedef __attribute__((ext_vector_type(8))) short s16x8;   // 8 bf16 (4 VGPR)
typedef __attribute__((ext_vector_type(4))) float f32x4;

__device__ __forceinline__ ushort f2bf(float f) {
  unsigned u = __float_as_uint(f);
  unsigned r = (u + 0x7fffu + ((u >> 16) & 1u)) >> 16;    // RNE
  return (ushort)r;
}
__device__ __forceinline__ float bf2f(ushort h) {
  return __uint_as_float(((unsigned)h) << 16);
}
__device__ __forceinline__ float bfl(unsigned u) { return __uint_as_float(u << 16); }
__device__ __forceinline__ float bfh(unsigned u) { return __uint_as_float(u & 0xffff0000u); }

// ---------------------------------------------------------------------------
// Weight convert + transpose, coalesced: fp32 in[K][N] -> bf16 out[N][K].
// 32x32 tiles via LDS (stride 33: conflict-free both phases).
// ---------------------------------------------------------------------------
struct TD { const float* in; ushort* out; int K; int N; };
struct TPack { TD d[10]; };

__global__ __launch_bounds__(256) void k_wconv(TPack p) {
  TD t = p.d[blockIdx.y];
  int ntk = t.K >> 5, ntn = t.N >> 5;
  int tile = blockIdx.x;
  if (tile >= ntk * ntn) return;
  int tn = tile / ntk, tk = tile - tn * ntk;
  __shared__ float ls[32 * 33];
  int tid = threadIdx.x;
  int r = tid >> 5, c = tid & 31;
#pragma unroll
  for (int i = 0; i < 4; ++i) {
    int kk = r + 8 * i;
    ls[kk * 33 + c] = t.in[(size_t)(tk * 32 + kk) * t.N + tn * 32 + c];
  }
  __syncthreads();
#pragma unroll
  for (int i = 0; i < 4; ++i) {
    int rr = r + 8 * i;
    t.out[(size_t)(tn * 32 + rr) * t.K + tk * 32 + c] = f2bf(ls[c * 33 + rr]);
  }
}

// ---------------------------------------------------------------------------
// Build x = inputs + PE, bf16 [R][128]
// ---------------------------------------------------------------------------
__global__ __launch_bounds__(256) void k_buildx(const float* __restrict__ inp,
                                                ushort* __restrict__ x) {
  int e = blockIdx.x * 256 + threadIdx.x;          // < R*128
  int i = e & 127, r = e >> 7;
  int n = r / (WMAX * BB);
  int rem = r - n * (WMAX * BB);
  int w = rem >> 1, b = rem & 1;
  int st = n - BLK; if (st < 0) st = 0;
  float pos = (float)(st + w);
  float div = __expf(-0.0719557841f * (float)(i & 126));
  float ang = pos * div;
  float pe = (i & 1) ? __cosf(ang) : __sinf(ang);
  x[e] = f2bf(inp[(n * BB + b) * DIN + i] + pe);
}

// ---------------------------------------------------------------------------
// kp = relu(inputs @ k_W1 + k_b1) @ k_W2 + k_b2   (fp32, tiny)
// ---------------------------------------------------------------------------
__global__ __launch_bounds__(256) void k_kp(
    const float* __restrict__ inp, const float* __restrict__ kW1,
    const float* __restrict__ kb1, const float* __restrict__ kW2,
    const float* __restrict__ kb2, float* __restrict__ kp) {
  __shared__ float xs[DIN];
  __shared__ float red[8];
  int row = blockIdx.x;
  int tid = threadIdx.x;
  if (tid < DIN) xs[tid] = inp[row * DIN + tid];
  __syncthreads();
  float a0 = 0.f, a1 = 0.f;
  for (int j = tid; j < DFF; j += 256) {
    float acc = kb1[j];
    for (int k = 0; k < DIN; ++k) acc += xs[k] * kW1[k * DFF + j];
    acc = fmaxf(acc, 0.f);
    a0 += acc * kW2[2 * j];
    a1 += acc * kW2[2 * j + 1];
  }
#pragma unroll
  for (int m = 32; m > 0; m >>= 1) {
    a0 += __shfl_xor(a0, m, 64);
    a1 += __shfl_xor(a1, m, 64);
  }
  if ((tid & 63) == 0) { red[(tid >> 6) * 2] = a0; red[(tid >> 6) * 2 + 1] = a1; }
  __syncthreads();
  if (tid == 0) {
    kp[row * 2 + 0] = red[0] + red[2] + red[4] + red[6] + kb2[0];
    kp[row * 2 + 1] = red[1] + red[3] + red[5] + red[7] + kb2[1];
  }
}

// ---------------------------------------------------------------------------
// 8-wave MFMA GEMM, BN=256: out[M][N] = A[M][K] @ Bt[N][K]^T + bias
//   [relu] or [+resid, LayerNorm] fused epilogue.
//   Waves: 2 (rows) x 4 (cols); wave tile (BMT/2) x 64.
// ---------------------------------------------------------------------------
template<int BMT, int RELU, int FUSE_LN>
__global__ __launch_bounds__(512) void k_gemm8(
    const ushort* __restrict__ A, const ushort* __restrict__ Bt,
    const float* __restrict__ bias, const ushort* __restrict__ resid,
    const float* __restrict__ lng, const float* __restrict__ lnb,
    ushort* __restrict__ out, int N, int K) {
  constexpr int MF = BMT / 32;                      // m-frags per wave
  __shared__ __align__(16) char As[BMT * 128];      // BMT x 64 bf16, swizzled
  __shared__ __align__(16) char Bs[256 * 128];      // 256 x 64 bf16, swizzled
  __shared__ float psum[FUSE_LN ? 4 : 1][FUSE_LN ? BMT : 1];
  __shared__ float psq [FUSE_LN ? 4 : 1][FUSE_LN ? BMT : 1];
  int tid = threadIdx.x;
  int m0 = blockIdx.x * BMT, n0 = blockIdx.y * 256;
  int lane = tid & 63, w = tid >> 6;
  int wr = w >> 2, wc = w & 3;
  int fr = lane & 15, g = lane >> 4;
  f32x4 acc[MF][4] = {};

  for (int kb = 0; kb < K; kb += 64) {
    __syncthreads();
#pragma unroll
    for (int it = 0; it < BMT / 64; ++it) {
      int e = tid + it * 512;
      int row = e >> 3, c = e & 7;
      uint4 v = *(const uint4*)(A + (size_t)(m0 + row) * K + kb + c * 8);
      *(uint4*)(As + ((row * 128 + c * 16) ^ ((row & 7) << 4))) = v;
    }
#pragma unroll
    for (int it = 0; it < 4; ++it) {
      int e = tid + it * 512;
      int row = e >> 3, c = e & 7;
      uint4 v = *(const uint4*)(Bt + (size_t)(n0 + row) * K + kb + c * 8);
      *(uint4*)(Bs + ((row * 128 + c * 16) ^ ((row & 7) << 4))) = v;
    }
    __syncthreads();
#pragma unroll
    for (int ks = 0; ks < 2; ++ks) {
      int kByte = ks * 64 + g * 16;
      s16x8 a[MF], b[4];
#pragma unroll
      for (int m = 0; m < MF; ++m) {
        int row = wr * (BMT / 2) + m * 16 + fr;
        a[m] = *(const s16x8*)(As + ((row * 128 + kByte) ^ ((row & 7) << 4)));
      }
#pragma unroll
      for (int n = 0; n < 4; ++n) {
        int row = wc * 64 + n * 16 + fr;
        b[n] = *(const s16x8*)(Bs + ((row * 128 + kByte) ^ ((row & 7) << 4)));
      }
#pragma unroll
      for (int m = 0; m < MF; ++m)
#pragma unroll
        for (int n = 0; n < 4; ++n)
          acc[m][n] = __builtin_amdgcn_mfma_f32_16x16x32_bf16(a[m], b[n], acc[m][n], 0, 0, 0);
    }
  }

  if constexpr (!FUSE_LN) {
#pragma unroll
    for (int m = 0; m < MF; ++m) {
      int rowb = m0 + wr * (BMT / 2) + m * 16 + g * 4;
#pragma unroll
      for (int n = 0; n < 4; ++n) {
        int col = n0 + wc * 64 + n * 16 + fr;
        float bv = bias[col];
#pragma unroll
        for (int j = 0; j < 4; ++j) {
          float v = acc[m][n][j] + bv;
          if (RELU) v = fmaxf(v, 0.f);
          out[(size_t)(rowb + j) * N + col] = f2bf(v);
        }
      }
    }
  } else {
    // z = acc + bias + resid; LN over the 256 cols (all in this block)
#pragma unroll
    for (int m = 0; m < MF; ++m) {
      int rowb = wr * (BMT / 2) + m * 16 + g * 4;     // local row base
#pragma unroll
      for (int j = 0; j < 4; ++j) {
        float ps = 0.f, pq = 0.f;
#pragma unroll
        for (int n = 0; n < 4; ++n) {
          int col = wc * 64 + n * 16 + fr;
          float v = acc[m][n][j] + bias[col]
                  + bf2f(resid[(size_t)(m0 + rowb + j) * 256 + col]);
          acc[m][n][j] = v;
          ps += v; pq += v * v;
        }
#pragma unroll
        for (int d = 1; d < 16; d <<= 1) {
          ps += __shfl_xor(ps, d, 64);
          pq += __shfl_xor(pq, d, 64);
        }
        if (fr == 0) { psum[wc][rowb + j] = ps; psq[wc][rowb + j] = pq; }
      }
    }
    __syncthreads();
#pragma unroll
    for (int m = 0; m < MF; ++m) {
      int rowb = wr * (BMT / 2) + m * 16 + g * 4;
#pragma unroll
      for (int j = 0; j < 4; ++j) {
        int lr = rowb + j;
        float sm = psum[0][lr] + psum[1][lr] + psum[2][lr] + psum[3][lr];
        float sq = psq[0][lr] + psq[1][lr] + psq[2][lr] + psq[3][lr];
        float mean = sm * (1.f / 256.f);
        float var = sq * (1.f / 256.f) - mean * mean;
        float rs = rsqrtf(var + 1e-5f);
#pragma unroll
        for (int n = 0; n < 4; ++n) {
          int col = wc * 64 + n * 16 + fr;
          float v = (acc[m][n][j] - mean) * rs * lng[col] + lnb[col];
          out[(size_t)(m0 + lr) * 256 + col] = f2bf(v);
        }
      }
    }
  }
}

// ---------------------------------------------------------------------------
// MFMA windowed attention. One block per (n,b,head), 5 waves.
// ---------------------------------------------------------------------------
constexpr int QKS = 40;    // Q/K LDS row stride (ushorts)
constexpr int VTS = 104;   // Vt LDS row stride
constexpr int PS  = 104;   // P  LDS row stride

__global__ __launch_bounds__(320) void k_attn(
    const ushort* __restrict__ qkv, ushort* __restrict__ o,
    const int* __restrict__ lenp) {
  __shared__ __align__(16) ushort Qs[80 * QKS];
  __shared__ __align__(16) ushort Ks[80 * QKS];
  __shared__ __align__(16) ushort Vt[32 * VTS];
  __shared__ __align__(16) ushort Pb[5 * 16 * PS];
  int L = lenp[0];
  int blk = blockIdx.x;
  int hh = blk & 7;
  int nb = blk >> 3;
  int b = nb & 1;
  int n = nb >> 1;
  int s0 = n - BLK; if (s0 < 0) s0 = 0;
  int e0 = n + BLK + 1; if (e0 > L) e0 = L;
  int vn = e0 - s0;
  int tid = threadIdx.x;

  for (int i = tid; i < 32 * VTS / 2; i += 320) ((uint*)Vt)[i] = 0;
  for (int i = tid; i < 15 * QKS / 2; i += 320) {
    ((uint*)(Qs + 65 * QKS))[i] = 0;
    ((uint*)(Ks + 65 * QKS))[i] = 0;
  }
  for (int e = tid; e < 65 * 4; e += 320) {
    int r = e >> 2, c = e & 3;
    const ushort* base = qkv + ((size_t)(n * WMAX + r) * BB + b) * (3 * DD) + hh * DH;
    *(uint4*)(Qs + r * QKS + c * 8) = *(const uint4*)(base + c * 8);
    *(uint4*)(Ks + r * QKS + c * 8) = *(const uint4*)(base + DD + c * 8);
    uint4 vv = *(const uint4*)(base + 2 * DD + c * 8);
    const ushort* vp = (const ushort*)&vv;
#pragma unroll
    for (int u = 0; u < 8; ++u) Vt[(c * 8 + u) * VTS + r] = vp[u];
  }
  __syncthreads();

  int w = tid >> 6, lane = tid & 63;
  int fr = lane & 15, g = lane >> 4;
  int q0 = w * 16;
  ushort* Pw = Pb + w * 16 * PS;

  s16x8 aq = *(const s16x8*)(Qs + (q0 + fr) * QKS + g * 8);
  f32x4 sacc[5];
#pragma unroll
  for (int t = 0; t < 5; ++t) {
    s16x8 bk = *(const s16x8*)(Ks + (t * 16 + fr) * QKS + g * 8);
    f32x4 z = {0.f, 0.f, 0.f, 0.f};
    sacc[t] = __builtin_amdgcn_mfma_f32_16x16x32_bf16(aq, bk, z, 0, 0, 0);
  }
  const float scl = 0.17677669529663687f;
#pragma unroll
  for (int j = 0; j < 4; ++j) {
    float pv[5];
    float mx = -3e38f;
#pragma unroll
    for (int t = 0; t < 5; ++t) {
      bool ok = (t * 16 + fr) < vn;
      pv[t] = ok ? sacc[t][j] * scl : -3e38f;
      mx = fmaxf(mx, pv[t]);
    }
#pragma unroll
    for (int d = 1; d < 16; d <<= 1) mx = fmaxf(mx, __shfl_xor(mx, d, 64));
    float sum = 0.f;
#pragma unroll
    for (int t = 0; t < 5; ++t) {
      float e = ((t * 16 + fr) < vn) ? __expf(pv[t] - mx) : 0.f;
      pv[t] = e;
      sum += e;
    }
#pragma unroll
    for (int d = 1; d < 16; d <<= 1) sum += __shfl_xor(sum, d, 64);
    float inv = 1.f / sum;
#pragma unroll
    for (int t = 0; t < 5; ++t)
      Pw[(g * 4 + j) * PS + t * 16 + fr] = f2bf(pv[t] * inv);
  }
  {
    int zr = lane >> 2, zc = 80 + (lane & 3) * 4;
    *(uint2*)(Pw + zr * PS + zc) = make_uint2(0u, 0u);
  }
  __syncthreads();

  f32x4 oacc[2] = {};
#pragma unroll
  for (int k0 = 0; k0 < 3; ++k0) {
    s16x8 ap = *(const s16x8*)(Pw + fr * PS + k0 * 32 + g * 8);
#pragma unroll
    for (int nt = 0; nt < 2; ++nt) {
      s16x8 bv = *(const s16x8*)(Vt + (nt * 16 + fr) * VTS + k0 * 32 + g * 8);
      oacc[nt] = __builtin_amdgcn_mfma_f32_16x16x32_bf16(ap, bv, oacc[nt], 0, 0, 0);
    }
  }
#pragma unroll
  for (int nt = 0; nt < 2; ++nt) {
#pragma unroll
    for (int j = 0; j < 4; ++j) {
      int qr = q0 + g * 4 + j;
      if (qr < WMAX)
        o[((size_t)(n * WMAX + qr) * BB + b) * DD + hh * DH + nt * 16 + fr] =
            f2bf(oacc[nt][j]);
    }
  }
}

// ---------------------------------------------------------------------------
// Final hierarchical softmax-gather (h bf16)
// ---------------------------------------------------------------------------
__global__ __launch_bounds__(256) void k_final(
    const ushort* __restrict__ h, const float* __restrict__ kp,
    float* __restrict__ out, const int* __restrict__ lenp) {
  int L = lenp[0];
  int t = blockIdx.x >> 1, b = blockIdx.x & 1;
  float hsc = (float)L / (float)NN;
  int nlo = t - BLK; if (nlo < 0) nlo = 0;
  int nhi = t + BLK; if (nhi > NN - 1) nhi = NN - 1;
  float mx = -3e38f;
  for (int n = nlo; n <= nhi; ++n) {
    float kp0 = kp[(n * BB + b) * 2 + 0];
    float kp1 = kp[(n * BB + b) * 2 + 1];
    float dif = (float)t - (float)n * hsc - kp0;
    float lg = -dif * dif * __expf(kp1);
    mx = fmaxf(mx, lg);
  }
  float sum = 0.f, acc = 0.f;
  int c = threadIdx.x;
  for (int n = nlo; n <= nhi; ++n) {
    float kp0 = kp[(n * BB + b) * 2 + 0];
    float kp1 = kp[(n * BB + b) * 2 + 1];
    float dif = (float)t - (float)n * hsc - kp0;
    float lg = -dif * dif * __expf(kp1);
    float p = __expf(lg - mx);
    sum += p;
    int st = n - BLK; if (st < 0) st = 0;
    int w = t - st;
    acc += p * bf2f(h[(size_t)((n * WMAX + w) * BB + b) * DD + c]);
  }
  out[(size_t)(t * BB + b) * DD + c] = acc / sum;
}

// ---------------------------------------------------------------------------
extern "C" void kernel_launch(void* const* d_in, const int* in_sizes, int n_in,
                              void* d_out, int out_size, void* d_ws, size_t ws_size,
                              hipStream_t stream) {
  const float* inputs = (const float*)d_in[0];
  const float* in_W1  = (const float*)d_in[1];
  const float* in_b1  = (const float*)d_in[2];
  const float* in_W2  = (const float*)d_in[3];
  const float* in_b2  = (const float*)d_in[4];
  const float* k_W1   = (const float*)d_in[5];
  const float* k_b1   = (const float*)d_in[6];
  const float* k_W2   = (const float*)d_in[7];
  const float* k_b2   = (const float*)d_in[8];
  const float* Wqkv   = (const float*)d_in[9];
  const float* bqkv   = (const float*)d_in[10];
  const float* Wo     = (const float*)d_in[11];
  const float* bo     = (const float*)d_in[12];
  const float* ln1_g  = (const float*)d_in[13];
  const float* ln1_b  = (const float*)d_in[14];
  const float* W1     = (const float*)d_in[15];
  const float* b1     = (const float*)d_in[16];
  const float* W2     = (const float*)d_in[17];
  const float* b2     = (const float*)d_in[18];
  const float* ln2_g  = (const float*)d_in[19];
  const float* ln2_b  = (const float*)d_in[20];
  const int*   lenp   = (const int*)d_in[21];
  float* out = (float*)d_out;
  (void)in_sizes; (void)n_in; (void)ws_size;

  ushort* wsu = (ushort*)d_ws;
  size_t off = 0;
  auto alloc = [&](size_t nelem) { ushort* p = wsu + off; off += (nelem + 7) & ~7ull; return p; };
  ushort* inW1t = alloc((size_t)DFF * DIN);
  ushort* inW2t = alloc((size_t)DD * DFF);
  ushort* Wqkvt = alloc((size_t)NL * 3 * DD * DD);
  ushort* Wot   = alloc((size_t)NL * DD * DD);
  ushort* W1t   = alloc((size_t)NL * DFF * DD);
  ushort* W2t   = alloc((size_t)NL * DD * DFF);
  ushort* x     = alloc((size_t)RROWS * DIN);
  ushort* tq    = alloc((size_t)RROWS * DFF);
  ushort* hb    = alloc((size_t)RROWS * DD);
  ushort* ob    = alloc((size_t)RROWS * DD);
  float*  kp    = (float*)(wsu + off);

  int L = out_size / (BB * DD);                      // 160

  TPack tp;
  tp.d[0] = {in_W1, inW1t, DIN, DFF};
  tp.d[1] = {in_W2, inW2t, DFF, DD};
  tp.d[2] = {Wqkv,                        Wqkvt,                       DD, 3 * DD};
  tp.d[3] = {Wqkv + (size_t)DD * 3 * DD,  Wqkvt + (size_t)3 * DD * DD, DD, 3 * DD};
  tp.d[4] = {Wo,                    Wot,                   DD, DD};
  tp.d[5] = {Wo + (size_t)DD * DD,  Wot + (size_t)DD * DD, DD, DD};
  tp.d[6] = {W1,                      W1t,                    DD, DFF};
  tp.d[7] = {W1 + (size_t)DD * DFF,   W1t + (size_t)DFF * DD, DD, DFF};
  tp.d[8] = {W2,                      W2t,                    DFF, DD};
  tp.d[9] = {W2 + (size_t)DFF * DD,   W2t + (size_t)DD * DFF, DFF, DD};
  k_wconv<<<dim3(256, 10), 256, 0, stream>>>(tp);

  k_buildx<<<RROWS * DIN / 256, 256, 0, stream>>>(inputs, x);
  k_kp<<<NN * BB, 256, 0, stream>>>(inputs, k_W1, k_b1, k_W2, k_b2, kp);

  // input MLP
  k_gemm8<128, 1, 0><<<dim3(RROWS / 128, 4), 512, 0, stream>>>(
      x, inW1t, in_b1, nullptr, nullptr, nullptr, tq, DFF, DIN);
  k_gemm8<64, 0, 0><<<dim3(RROWS / 64, 1), 512, 0, stream>>>(
      tq, inW2t, in_b2, nullptr, nullptr, nullptr, hb, DD, DFF);

  for (int l = 0; l < NL; ++l) {
    k_gemm8<128, 0, 0><<<dim3(RROWS / 128, 3), 512, 0, stream>>>(
        hb, Wqkvt + (size_t)l * 3 * DD * DD, bqkv + (size_t)l * 3 * DD,
        nullptr, nullptr, nullptr, tq, 3 * DD, DD);
    k_attn<<<NN * BB * NH, 320, 0, stream>>>(tq, ob, lenp);
    k_gemm8<64, 0, 1><<<dim3(RROWS / 64, 1), 512, 0, stream>>>(
        ob, Wot + (size_t)l * DD * DD, bo + (size_t)l * DD, hb,
        ln1_g + (size_t)l * DD, ln1_b + (size_t)l * DD, hb, DD, DD);
    k_gemm8<128, 1, 0><<<dim3(RROWS / 128, 4), 512, 0, stream>>>(
        hb, W1t + (size_t)l * DFF * DD, b1 + (size_t)l * DFF,
        nullptr, nullptr, nullptr, tq, DFF, DD);
    k_gemm8<64, 0, 1><<<dim3(RROWS / 64, 1), 512, 0, stream>>>(
        tq, W2t + (size_t)l * DD * DFF, b2 + (size_t)l * DD, hb,
        ln2_g + (size_t)l * DD, ln2_b + (size_t)l * DD, hb, DD, DFF);
  }
  k_final<<<L * BB, 256, 0, stream>>>(hb, kp, out, lenp);
}

// Round 5
// 285.587 us; speedup vs baseline: 7.1264x; 1.0385x over previous
//
#include <hip/hip_runtime.h>

constexpr int NN    = 128;
constexpr int BB    = 2;
constexpr int DIN   = 128;
constexpr int DD    = 256;
constexpr int DFF   = 1024;
constexpr int NH    = 8;
constexpr int DH    = 32;
constexpr int NL    = 2;
constexpr int BLK   = 32;
constexpr int WMAX  = 2 * BLK + 1;       // 65
constexpr int RROWS = NN * WMAX * BB;    // 16640

typedef __attribute__((ext_vector_type(8))) short s16x8;   // 8 bf16 (4 VGPR)
typedef __attribute__((ext_vector_type(4))) float f32x4;

__device__ __forceinline__ ushort f2bf(float f) {
  unsigned u = __float_as_uint(f);
  unsigned r = (u + 0x7fffu + ((u >> 16) & 1u)) >> 16;    // RNE
  return (ushort)r;
}
__device__ __forceinline__ float bf2f(ushort h) {
  return __uint_as_float(((unsigned)h) << 16);
}
__device__ __forceinline__ float bfl(unsigned u) { return __uint_as_float(u << 16); }
__device__ __forceinline__ float bfh(unsigned u) { return __uint_as_float(u & 0xffff0000u); }

// async global->LDS, 16B per lane; LDS dest must be lane-linear.
__device__ __forceinline__ void gld16(const void* g, void* l) {
  __builtin_amdgcn_global_load_lds(
      (const __attribute__((address_space(1))) void*)g,
      (__attribute__((address_space(3))) void*)l, 16, 0, 0);
}

// ---------------------------------------------------------------------------
// Weight convert + transpose, coalesced: fp32 in[K][N] -> bf16 out[N][K].
// ---------------------------------------------------------------------------
struct TD { const float* in; ushort* out; int K; int N; };
struct TPack { TD d[10]; };

__global__ __launch_bounds__(256) void k_wconv(TPack p) {
  TD t = p.d[blockIdx.y];
  int ntk = t.K >> 5, ntn = t.N >> 5;
  int tile = blockIdx.x;
  if (tile >= ntk * ntn) return;
  int tn = tile / ntk, tk = tile - tn * ntk;
  __shared__ float ls[32 * 33];
  int tid = threadIdx.x;
  int r = tid >> 5, c = tid & 31;
#pragma unroll
  for (int i = 0; i < 4; ++i) {
    int kk = r + 8 * i;
    ls[kk * 33 + c] = t.in[(size_t)(tk * 32 + kk) * t.N + tn * 32 + c];
  }
  __syncthreads();
#pragma unroll
  for (int i = 0; i < 4; ++i) {
    int rr = r + 8 * i;
    t.out[(size_t)(tn * 32 + rr) * t.K + tk * 32 + c] = f2bf(ls[c * 33 + rr]);
  }
}

// ---------------------------------------------------------------------------
// Build x = inputs + PE, bf16 [R][128]
// ---------------------------------------------------------------------------
__global__ __launch_bounds__(256) void k_buildx(const float* __restrict__ inp,
                                                ushort* __restrict__ x) {
  int e = blockIdx.x * 256 + threadIdx.x;          // < R*128
  int i = e & 127, r = e >> 7;
  int n = r / (WMAX * BB);
  int rem = r - n * (WMAX * BB);
  int w = rem >> 1, b = rem & 1;
  int st = n - BLK; if (st < 0) st = 0;
  float pos = (float)(st + w);
  float div = __expf(-0.0719557841f * (float)(i & 126));
  float ang = pos * div;
  float pe = (i & 1) ? __cosf(ang) : __sinf(ang);
  x[e] = f2bf(inp[(n * BB + b) * DIN + i] + pe);
}

// ---------------------------------------------------------------------------
// kp = relu(inputs @ k_W1 + k_b1) @ k_W2 + k_b2   (fp32, tiny)
// ---------------------------------------------------------------------------
__global__ __launch_bounds__(256) void k_kp(
    const float* __restrict__ inp, const float* __restrict__ kW1,
    const float* __restrict__ kb1, const float* __restrict__ kW2,
    const float* __restrict__ kb2, float* __restrict__ kp) {
  __shared__ float xs[DIN];
  __shared__ float red[8];
  int row = blockIdx.x;
  int tid = threadIdx.x;
  if (tid < DIN) xs[tid] = inp[row * DIN + tid];
  __syncthreads();
  float a0 = 0.f, a1 = 0.f;
  for (int j = tid; j < DFF; j += 256) {
    float acc = kb1[j];
    for (int k = 0; k < DIN; ++k) acc += xs[k] * kW1[k * DFF + j];
    acc = fmaxf(acc, 0.f);
    a0 += acc * kW2[2 * j];
    a1 += acc * kW2[2 * j + 1];
  }
#pragma unroll
  for (int m = 32; m > 0; m >>= 1) {
    a0 += __shfl_xor(a0, m, 64);
    a1 += __shfl_xor(a1, m, 64);
  }
  if ((tid & 63) == 0) { red[(tid >> 6) * 2] = a0; red[(tid >> 6) * 2 + 1] = a1; }
  __syncthreads();
  if (tid == 0) {
    kp[row * 2 + 0] = red[0] + red[2] + red[4] + red[6] + kb2[0];
    kp[row * 2 + 1] = red[1] + red[3] + red[5] + red[7] + kb2[1];
  }
}

// ---------------------------------------------------------------------------
// 8-wave MFMA GEMM, BN=256, global_load_lds staging (pre-swizzled source).
// ---------------------------------------------------------------------------
template<int BMT, int RELU, int FUSE_LN>
__global__ __launch_bounds__(512) void k_gemm8(
    const ushort* __restrict__ A, const ushort* __restrict__ Bt,
    const float* __restrict__ bias, const ushort* __restrict__ resid,
    const float* __restrict__ lng, const float* __restrict__ lnb,
    ushort* __restrict__ out, int N, int K) {
  constexpr int MF = BMT / 32;                      // m-frags per wave
  __shared__ __align__(16) char As[BMT * 128];      // BMT x 64 bf16, swizzled
  __shared__ __align__(16) char Bs[256 * 128];      // 256 x 64 bf16, swizzled
  __shared__ float psum[FUSE_LN ? 4 : 1][FUSE_LN ? BMT : 1];
  __shared__ float psq [FUSE_LN ? 4 : 1][FUSE_LN ? BMT : 1];
  int tid = threadIdx.x;
  int m0 = blockIdx.x * BMT, n0 = blockIdx.y * 256;
  int lane = tid & 63, w = tid >> 6;
  int wr = w >> 2, wc = w & 3;
  int fr = lane & 15, g = lane >> 4;
  f32x4 acc[MF][4] = {};

  for (int kb = 0; kb < K; kb += 64) {
    __syncthreads();
    // A: LDS slot e*16 receives source chunk (c ^ (row&7)) -> reads use the
    // same XOR and land on the right data. Dest is lane-linear (e*16).
#pragma unroll
    for (int it = 0; it < BMT / 64; ++it) {
      int e = tid + it * 512;
      int row = e >> 3, c = e & 7;
      gld16(A + (size_t)(m0 + row) * K + kb + ((c ^ (row & 7)) * 8), As + e * 16);
    }
#pragma unroll
    for (int it = 0; it < 4; ++it) {
      int e = tid + it * 512;
      int row = e >> 3, c = e & 7;
      gld16(Bt + (size_t)(n0 + row) * K + kb + ((c ^ (row & 7)) * 8), Bs + e * 16);
    }
    __syncthreads();
#pragma unroll
    for (int ks = 0; ks < 2; ++ks) {
      int kByte = ks * 64 + g * 16;
      s16x8 a[MF], b[4];
#pragma unroll
      for (int m = 0; m < MF; ++m) {
        int row = wr * (BMT / 2) + m * 16 + fr;
        a[m] = *(const s16x8*)(As + ((row * 128 + kByte) ^ ((row & 7) << 4)));
      }
#pragma unroll
      for (int n = 0; n < 4; ++n) {
        int row = wc * 64 + n * 16 + fr;
        b[n] = *(const s16x8*)(Bs + ((row * 128 + kByte) ^ ((row & 7) << 4)));
      }
#pragma unroll
      for (int m = 0; m < MF; ++m)
#pragma unroll
        for (int n = 0; n < 4; ++n)
          acc[m][n] = __builtin_amdgcn_mfma_f32_16x16x32_bf16(a[m], b[n], acc[m][n], 0, 0, 0);
    }
  }

  if constexpr (!FUSE_LN) {
#pragma unroll
    for (int m = 0; m < MF; ++m) {
      int rowb = m0 + wr * (BMT / 2) + m * 16 + g * 4;
#pragma unroll
      for (int n = 0; n < 4; ++n) {
        int col = n0 + wc * 64 + n * 16 + fr;
        float bv = bias[col];
#pragma unroll
        for (int j = 0; j < 4; ++j) {
          float v = acc[m][n][j] + bv;
          if (RELU) v = fmaxf(v, 0.f);
          out[(size_t)(rowb + j) * N + col] = f2bf(v);
        }
      }
    }
  } else {
#pragma unroll
    for (int m = 0; m < MF; ++m) {
      int rowb = wr * (BMT / 2) + m * 16 + g * 4;     // local row base
#pragma unroll
      for (int j = 0; j < 4; ++j) {
        float ps = 0.f, pq = 0.f;
#pragma unroll
        for (int n = 0; n < 4; ++n) {
          int col = wc * 64 + n * 16 + fr;
          float v = acc[m][n][j] + bias[col]
                  + bf2f(resid[(size_t)(m0 + rowb + j) * 256 + col]);
          acc[m][n][j] = v;
          ps += v; pq += v * v;
        }
#pragma unroll
        for (int d = 1; d < 16; d <<= 1) {
          ps += __shfl_xor(ps, d, 64);
          pq += __shfl_xor(pq, d, 64);
        }
        if (fr == 0) { psum[wc][rowb + j] = ps; psq[wc][rowb + j] = pq; }
      }
    }
    __syncthreads();
#pragma unroll
    for (int m = 0; m < MF; ++m) {
      int rowb = wr * (BMT / 2) + m * 16 + g * 4;
#pragma unroll
      for (int j = 0; j < 4; ++j) {
        int lr = rowb + j;
        float sm = psum[0][lr] + psum[1][lr] + psum[2][lr] + psum[3][lr];
        float sq = psq[0][lr] + psq[1][lr] + psq[2][lr] + psq[3][lr];
        float mean = sm * (1.f / 256.f);
        float var = sq * (1.f / 256.f) - mean * mean;
        float rs = rsqrtf(var + 1e-5f);
#pragma unroll
        for (int n = 0; n < 4; ++n) {
          int col = wc * 64 + n * 16 + fr;
          float v = (acc[m][n][j] - mean) * rs * lng[col] + lnb[col];
          out[(size_t)(m0 + lr) * 256 + col] = f2bf(v);
        }
      }
    }
  }
}

// ---------------------------------------------------------------------------
// MFMA windowed attention. One block per (n,b,head), 5 waves.
// Vt uses an XOR r-chunk swizzle to kill the 32-way transpose-write conflict.
// ---------------------------------------------------------------------------
constexpr int QKS = 40;    // Q/K LDS row stride (ushorts)
constexpr int VTS = 104;   // Vt LDS row stride (d-major: [32][104])
constexpr int PS  = 104;   // P  LDS row stride

__device__ __forceinline__ int vslot(int d, int r) {
  int rc = r >> 3;
  int sw = (rc < 8) ? (rc ^ (d >> 3)) : rc;     // d>>3 in [0,4)
  return d * VTS + sw * 8 + (r & 7);
}

__global__ __launch_bounds__(320) void k_attn(
    const ushort* __restrict__ qkv, ushort* __restrict__ o,
    const int* __restrict__ lenp) {
  __shared__ __align__(16) ushort Qs[80 * QKS];
  __shared__ __align__(16) ushort Ks[80 * QKS];
  __shared__ __align__(16) ushort Vt[32 * VTS];
  __shared__ __align__(16) ushort Pb[5 * 16 * PS];
  int L = lenp[0];
  int blk = blockIdx.x;
  int hh = blk & 7;
  int nb = blk >> 3;
  int b = nb & 1;
  int n = nb >> 1;
  int s0 = n - BLK; if (s0 < 0) s0 = 0;
  int e0 = n + BLK + 1; if (e0 > L) e0 = L;
  int vn = e0 - s0;
  int tid = threadIdx.x;

  for (int i = tid; i < 32 * VTS / 2; i += 320) ((uint*)Vt)[i] = 0;
  for (int i = tid; i < 15 * QKS / 2; i += 320) {
    ((uint*)(Qs + 65 * QKS))[i] = 0;
    ((uint*)(Ks + 65 * QKS))[i] = 0;
  }
  for (int e = tid; e < 65 * 4; e += 320) {
    int r = e >> 2, c = e & 3;
    const ushort* base = qkv + ((size_t)(n * WMAX + r) * BB + b) * (3 * DD) + hh * DH;
    *(uint4*)(Qs + r * QKS + c * 8) = *(const uint4*)(base + c * 8);
    *(uint4*)(Ks + r * QKS + c * 8) = *(const uint4*)(base + DD + c * 8);
    uint4 vv = *(const uint4*)(base + 2 * DD + c * 8);
    const ushort* vp = (const ushort*)&vv;
#pragma unroll
    for (int u = 0; u < 8; ++u) Vt[vslot(c * 8 + u, r)] = vp[u];
  }
  __syncthreads();

  int w = tid >> 6, lane = tid & 63;
  int fr = lane & 15, g = lane >> 4;
  int q0 = w * 16;
  ushort* Pw = Pb + w * 16 * PS;

  s16x8 aq = *(const s16x8*)(Qs + (q0 + fr) * QKS + g * 8);
  f32x4 sacc[5];
#pragma unroll
  for (int t = 0; t < 5; ++t) {
    s16x8 bk = *(const s16x8*)(Ks + (t * 16 + fr) * QKS + g * 8);
    f32x4 z = {0.f, 0.f, 0.f, 0.f};
    sacc[t] = __builtin_amdgcn_mfma_f32_16x16x32_bf16(aq, bk, z, 0, 0, 0);
  }
  const float scl = 0.17677669529663687f;
#pragma unroll
  for (int j = 0; j < 4; ++j) {
    float pv[5];
    float mx = -3e38f;
#pragma unroll
    for (int t = 0; t < 5; ++t) {
      bool ok = (t * 16 + fr) < vn;
      pv[t] = ok ? sacc[t][j] * scl : -3e38f;
      mx = fmaxf(mx, pv[t]);
    }
#pragma unroll
    for (int d = 1; d < 16; d <<= 1) mx = fmaxf(mx, __shfl_xor(mx, d, 64));
    float sum = 0.f;
#pragma unroll
    for (int t = 0; t < 5; ++t) {
      float e = ((t * 16 + fr) < vn) ? __expf(pv[t] - mx) : 0.f;
      pv[t] = e;
      sum += e;
    }
#pragma unroll
    for (int d = 1; d < 16; d <<= 1) sum += __shfl_xor(sum, d, 64);
    float inv = 1.f / sum;
#pragma unroll
    for (int t = 0; t < 5; ++t)
      Pw[(g * 4 + j) * PS + t * 16 + fr] = f2bf(pv[t] * inv);
  }
  {
    int zr = lane >> 2, zc = 80 + (lane & 3) * 4;
    *(uint2*)(Pw + zr * PS + zc) = make_uint2(0u, 0u);
  }
  __syncthreads();

  f32x4 oacc[2] = {};
#pragma unroll
  for (int k0 = 0; k0 < 3; ++k0) {
    s16x8 ap = *(const s16x8*)(Pw + fr * PS + k0 * 32 + g * 8);
#pragma unroll
    for (int nt = 0; nt < 2; ++nt) {
      // 8 contiguous r within one swizzled chunk: vslot(d, k0*32+g*8) starts it
      s16x8 bv = *(const s16x8*)(Vt + vslot(nt * 16 + fr, k0 * 32 + g * 8));
      oacc[nt] = __builtin_amdgcn_mfma_f32_16x16x32_bf16(ap, bv, oacc[nt], 0, 0, 0);
    }
  }
#pragma unroll
  for (int nt = 0; nt < 2; ++nt) {
#pragma unroll
    for (int j = 0; j < 4; ++j) {
      int qr = q0 + g * 4 + j;
      if (qr < WMAX)
        o[((size_t)(n * WMAX + qr) * BB + b) * DD + hh * DH + nt * 16 + fr] =
            f2bf(oacc[nt][j]);
    }
  }
}

// ---------------------------------------------------------------------------
// Final hierarchical softmax-gather (h bf16)
// ---------------------------------------------------------------------------
__global__ __launch_bounds__(256) void k_final(
    const ushort* __restrict__ h, const float* __restrict__ kp,
    float* __restrict__ out, const int* __restrict__ lenp) {
  int L = lenp[0];
  int t = blockIdx.x >> 1, b = blockIdx.x & 1;
  float hsc = (float)L / (float)NN;
  int nlo = t - BLK; if (nlo < 0) nlo = 0;
  int nhi = t + BLK; if (nhi > NN - 1) nhi = NN - 1;
  float mx = -3e38f;
  for (int n = nlo; n <= nhi; ++n) {
    float kp0 = kp[(n * BB + b) * 2 + 0];
    float kp1 = kp[(n * BB + b) * 2 + 1];
    float dif = (float)t - (float)n * hsc - kp0;
    float lg = -dif * dif * __expf(kp1);
    mx = fmaxf(mx, lg);
  }
  float sum = 0.f, acc = 0.f;
  int c = threadIdx.x;
  for (int n = nlo; n <= nhi; ++n) {
    float kp0 = kp[(n * BB + b) * 2 + 0];
    float kp1 = kp[(n * BB + b) * 2 + 1];
    float dif = (float)t - (float)n * hsc - kp0;
    float lg = -dif * dif * __expf(kp1);
    float p = __expf(lg - mx);
    sum += p;
    int st = n - BLK; if (st < 0) st = 0;
    int w = t - st;
    acc += p * bf2f(h[(size_t)((n * WMAX + w) * BB + b) * DD + c]);
  }
  out[(size_t)(t * BB + b) * DD + c] = acc / sum;
}

// ---------------------------------------------------------------------------
extern "C" void kernel_launch(void* const* d_in, const int* in_sizes, int n_in,
                              void* d_out, int out_size, void* d_ws, size_t ws_size,
                              hipStream_t stream) {
  const float* inputs = (const float*)d_in[0];
  const float* in_W1  = (const float*)d_in[1];
  const float* in_b1  = (const float*)d_in[2];
  const float* in_W2  = (const float*)d_in[3];
  const float* in_b2  = (const float*)d_in[4];
  const float* k_W1   = (const float*)d_in[5];
  const float* k_b1   = (const float*)d_in[6];
  const float* k_W2   = (const float*)d_in[7];
  const float* k_b2   = (const float*)d_in[8];
  const float* Wqkv   = (const float*)d_in[9];
  const float* bqkv   = (const float*)d_in[10];
  const float* Wo     = (const float*)d_in[11];
  const float* bo     = (const float*)d_in[12];
  const float* ln1_g  = (const float*)d_in[13];
  const float* ln1_b  = (const float*)d_in[14];
  const float* W1     = (const float*)d_in[15];
  const float* b1     = (const float*)d_in[16];
  const float* W2     = (const float*)d_in[17];
  const float* b2     = (const float*)d_in[18];
  const float* ln2_g  = (const float*)d_in[19];
  const float* ln2_b  = (const float*)d_in[20];
  const int*   lenp   = (const int*)d_in[21];
  float* out = (float*)d_out;
  (void)in_sizes; (void)n_in; (void)ws_size;

  ushort* wsu = (ushort*)d_ws;
  size_t off = 0;
  auto alloc = [&](size_t nelem) { ushort* p = wsu + off; off += (nelem + 7) & ~7ull; return p; };
  ushort* inW1t = alloc((size_t)DFF * DIN);
  ushort* inW2t = alloc((size_t)DD * DFF);
  ushort* Wqkvt = alloc((size_t)NL * 3 * DD * DD);
  ushort* Wot   = alloc((size_t)NL * DD * DD);
  ushort* W1t   = alloc((size_t)NL * DFF * DD);
  ushort* W2t   = alloc((size_t)NL * DD * DFF);
  ushort* x     = alloc((size_t)RROWS * DIN);
  ushort* tq    = alloc((size_t)RROWS * DFF);
  ushort* hb    = alloc((size_t)RROWS * DD);
  ushort* ob    = alloc((size_t)RROWS * DD);
  float*  kp    = (float*)(wsu + off);

  int L = out_size / (BB * DD);                      // 160

  TPack tp;
  tp.d[0] = {in_W1, inW1t, DIN, DFF};
  tp.d[1] = {in_W2, inW2t, DFF, DD};
  tp.d[2] = {Wqkv,                        Wqkvt,                       DD, 3 * DD};
  tp.d[3] = {Wqkv + (size_t)DD * 3 * DD,  Wqkvt + (size_t)3 * DD * DD, DD, 3 * DD};
  tp.d[4] = {Wo,                    Wot,                   DD, DD};
  tp.d[5] = {Wo + (size_t)DD * DD,  Wot + (size_t)DD * DD, DD, DD};
  tp.d[6] = {W1,                      W1t,                    DD, DFF};
  tp.d[7] = {W1 + (size_t)DD * DFF,   W1t + (size_t)DFF * DD, DD, DFF};
  tp.d[8] = {W2,                      W2t,                    DFF, DD};
  tp.d[9] = {W2 + (size_t)DFF * DD,   W2t + (size_t)DD * DFF, DFF, DD};
  k_wconv<<<dim3(256, 10), 256, 0, stream>>>(tp);

  k_buildx<<<RROWS * DIN / 256, 256, 0, stream>>>(inputs, x);
  k_kp<<<NN * BB, 256, 0, stream>>>(inputs, k_W1, k_b1, k_W2, k_b2, kp);

  // input MLP
  k_gemm8<128, 1, 0><<<dim3(RROWS / 128, 4), 512, 0, stream>>>(
      x, inW1t, in_b1, nullptr, nullptr, nullptr, tq, DFF, DIN);
  k_gemm8<64, 0, 0><<<dim3(RROWS / 64, 1), 512, 0, stream>>>(
      tq, inW2t, in_b2, nullptr, nullptr, nullptr, hb, DD, DFF);

  for (int l = 0; l < NL; ++l) {
    k_gemm8<128, 0, 0><<<dim3(RROWS / 128, 3), 512, 0, stream>>>(
        hb, Wqkvt + (size_t)l * 3 * DD * DD, bqkv + (size_t)l * 3 * DD,
        nullptr, nullptr, nullptr, tq, 3 * DD, DD);
    k_attn<<<NN * BB * NH, 320, 0, stream>>>(tq, ob, lenp);
    k_gemm8<64, 0, 1><<<dim3(RROWS / 64, 1), 512, 0, stream>>>(
        ob, Wot + (size_t)l * DD * DD, bo + (size_t)l * DD, hb,
        ln1_g + (size_t)l * DD, ln1_b + (size_t)l * DD, hb, DD, DD);
    k_gemm8<128, 1, 0><<<dim3(RROWS / 128, 4), 512, 0, stream>>>(
        hb, W1t + (size_t)l * DFF * DD, b1 + (size_t)l * DFF,
        nullptr, nullptr, nullptr, tq, DFF, DD);
    k_gemm8<64, 0, 1><<<dim3(RROWS / 64, 1), 512, 0, stream>>>(
        tq, W2t + (size_t)l * DD * DFF, b2 + (size_t)l * DD, hb,
        ln2_g + (size_t)l * DD, ln2_b + (size_t)l * DD, hb, DD, DFF);
  }
  k_final<<<L * BB, 256, 0, stream>>>(hb, kp, out, lenp);
}

// Round 8
// 268.120 us; speedup vs baseline: 7.5906x; 1.0651x over previous
//
#include <hip/hip_runtime.h>

constexpr int NN    = 128;
constexpr int BB    = 2;
constexpr int DIN   = 128;
constexpr int DD    = 256;
constexpr int DFF   = 1024;
constexpr int NH    = 8;
constexpr int DH    = 32;
constexpr int NL    = 2;
constexpr int BLK   = 32;
constexpr int WMAX  = 2 * BLK + 1;       // 65
constexpr int RROWS = NN * WMAX * BB;    // 16640

typedef __attribute__((ext_vector_type(8))) short s16x8;   // 8 bf16 (4 VGPR)
typedef __attribute__((ext_vector_type(4))) float f32x4;

__device__ __forceinline__ ushort f2bf(float f) {
  unsigned u = __float_as_uint(f);
  unsigned r = (u + 0x7fffu + ((u >> 16) & 1u)) >> 16;    // RNE
  return (ushort)r;
}
__device__ __forceinline__ float bf2f(ushort h) {
  return __uint_as_float(((unsigned)h) << 16);
}
__device__ __forceinline__ float bfl(unsigned u) { return __uint_as_float(u << 16); }
__device__ __forceinline__ float bfh(unsigned u) { return __uint_as_float(u & 0xffff0000u); }

// async global->LDS, 16B per lane; LDS dest must be lane-linear.
__device__ __forceinline__ void gld16(const void* g, void* l) {
  __builtin_amdgcn_global_load_lds(
      (const __attribute__((address_space(1))) void*)g,
      (__attribute__((address_space(3))) void*)l, 16, 0, 0);
}
// Explicit vmcnt drain: global_load_lds completion is tracked per-wave; the
// cross-wave LDS visibility contract is vmcnt(0) BEFORE the barrier (T3/T4).
__device__ __forceinline__ void vmdrain() {
  asm volatile("s_waitcnt vmcnt(0)" ::: "memory");
}

// ---------------------------------------------------------------------------
// Fused prep: [0,1920) weight transpose tiles, [1920,10240) buildx, [10240,
// 10496) kp rows.
// ---------------------------------------------------------------------------
struct TD { const float* in; ushort* out; int K; int N; };
struct TPack { TD d[10]; };
constexpr int WCONV_TILES = 1920;
constexpr int BX_BLOCKS   = RROWS * DIN / 256;   // 8320

__global__ __launch_bounds__(256) void k_prep(
    TPack p, const float* __restrict__ inp, ushort* __restrict__ x,
    const float* __restrict__ kW1, const float* __restrict__ kb1,
    const float* __restrict__ kW2, const float* __restrict__ kb2,
    float* __restrict__ kp) {
  __shared__ float ls[32 * 33];
  int bid = blockIdx.x;
  int tid = threadIdx.x;
  if (bid < WCONV_TILES) {
    const int cum[11] = {0, 128, 384, 576, 768, 832, 896, 1152, 1408, 1664, 1920};
    int mi = 0;
#pragma unroll
    for (int i = 0; i < 10; ++i) if (bid >= cum[i + 1]) mi = i + 1;
    TD t = p.d[mi];
    int tile = bid - cum[mi];
    int ntk = t.K >> 5;
    int tn = tile / ntk, tk = tile - tn * ntk;
    int r = tid >> 5, c = tid & 31;
#pragma unroll
    for (int i = 0; i < 4; ++i) {
      int kk = r + 8 * i;
      ls[kk * 33 + c] = t.in[(size_t)(tk * 32 + kk) * t.N + tn * 32 + c];
    }
    __syncthreads();
#pragma unroll
    for (int i = 0; i < 4; ++i) {
      int rr = r + 8 * i;
      t.out[(size_t)(tn * 32 + rr) * t.K + tk * 32 + c] = f2bf(ls[c * 33 + rr]);
    }
  } else if (bid < WCONV_TILES + BX_BLOCKS) {
    int e = (bid - WCONV_TILES) * 256 + tid;       // < R*128
    int i = e & 127, r = e >> 7;
    int n = r / (WMAX * BB);
    int rem = r - n * (WMAX * BB);
    int w = rem >> 1, b = rem & 1;
    int st = n - BLK; if (st < 0) st = 0;
    float pos = (float)(st + w);
    float div = __expf(-0.0719557841f * (float)(i & 126));
    float ang = pos * div;
    float pe = (i & 1) ? __cosf(ang) : __sinf(ang);
    x[e] = f2bf(inp[(n * BB + b) * DIN + i] + pe);
  } else {
    int row = bid - (WCONV_TILES + BX_BLOCKS);
    float* xs = ls;                  // reuse LDS
    float* red = ls + 256;
    if (tid < DIN) xs[tid] = inp[row * DIN + tid];
    __syncthreads();
    float a0 = 0.f, a1 = 0.f;
    for (int j = tid; j < DFF; j += 256) {
      float acc = kb1[j];
      for (int k = 0; k < DIN; ++k) acc += xs[k] * kW1[k * DFF + j];
      acc = fmaxf(acc, 0.f);
      a0 += acc * kW2[2 * j];
      a1 += acc * kW2[2 * j + 1];
    }
#pragma unroll
    for (int m = 32; m > 0; m >>= 1) {
      a0 += __shfl_xor(a0, m, 64);
      a1 += __shfl_xor(a1, m, 64);
    }
    if ((tid & 63) == 0) { red[(tid >> 6) * 2] = a0; red[(tid >> 6) * 2 + 1] = a1; }
    __syncthreads();
    if (tid == 0) {
      kp[row * 2 + 0] = red[0] + red[2] + red[4] + red[6] + kb2[0];
      kp[row * 2 + 1] = red[1] + red[3] + red[5] + red[7] + kb2[1];
    }
  }
}

// ---------------------------------------------------------------------------
// 8-wave MFMA GEMM, BN=256, global_load_lds staging (pre-swizzled source).
// DBUF=1: 2-phase double-buffered pipeline (stage t+1 before compute t),
// with explicit vmcnt(0) drain before each barrier (cross-wave LDS-DMA).
// ---------------------------------------------------------------------------
template<int BMT, int RELU, int FUSE_LN, int DBUF>
__global__ __launch_bounds__(512) void k_gemm8(
    const ushort* __restrict__ A, const ushort* __restrict__ Bt,
    const float* __restrict__ bias, const ushort* __restrict__ resid,
    const float* __restrict__ lng, const float* __restrict__ lnb,
    ushort* __restrict__ out, int N, int K) {
  constexpr int MF = BMT / 32;                         // m-frags per wave
  constexpr int NB = DBUF ? 2 : 1;
  __shared__ __align__(16) char As[NB * BMT * 128];
  __shared__ __align__(16) char Bs[NB * 256 * 128];
  int tid = threadIdx.x;
  int m0 = blockIdx.x * BMT, n0 = blockIdx.y * 256;
  int lane = tid & 63, w = tid >> 6;
  int wr = w >> 2, wc = w & 3;
  int fr = lane & 15, g = lane >> 4;
  f32x4 acc[MF][4] = {};

  auto stage = [&](int half, int tk) {
    int kb = tk * 64;
    char* Ah = As + half * (BMT * 128);
    char* Bh = Bs + half * (256 * 128);
#pragma unroll
    for (int it = 0; it < BMT / 64; ++it) {
      int e = tid + it * 512;
      int row = e >> 3, c = e & 7;
      gld16(A + (size_t)(m0 + row) * K + kb + ((c ^ (row & 7)) * 8), Ah + e * 16);
    }
#pragma unroll
    for (int it = 0; it < 4; ++it) {
      int e = tid + it * 512;
      int row = e >> 3, c = e & 7;
      gld16(Bt + (size_t)(n0 + row) * K + kb + ((c ^ (row & 7)) * 8), Bh + e * 16);
    }
  };
  auto compute = [&](int half) {
    const char* Ah = As + half * (BMT * 128);
    const char* Bh = Bs + half * (256 * 128);
#pragma unroll
    for (int ks = 0; ks < 2; ++ks) {
      int kByte = ks * 64 + g * 16;
      s16x8 a[MF], b[4];
#pragma unroll
      for (int m = 0; m < MF; ++m) {
        int row = wr * (BMT / 2) + m * 16 + fr;
        a[m] = *(const s16x8*)(Ah + ((row * 128 + kByte) ^ ((row & 7) << 4)));
      }
#pragma unroll
      for (int n = 0; n < 4; ++n) {
        int row = wc * 64 + n * 16 + fr;
        b[n] = *(const s16x8*)(Bh + ((row * 128 + kByte) ^ ((row & 7) << 4)));
      }
#pragma unroll
      for (int m = 0; m < MF; ++m)
#pragma unroll
        for (int n = 0; n < 4; ++n)
          acc[m][n] = __builtin_amdgcn_mfma_f32_16x16x32_bf16(a[m], b[n], acc[m][n], 0, 0, 0);
    }
  };

  int nt = K >> 6;
  if constexpr (DBUF) {
    stage(0, 0);
    vmdrain();
    __syncthreads();
    for (int t = 0; t < nt; ++t) {
      if (t + 1 < nt) stage((t + 1) & 1, t + 1);
      compute(t & 1);
      vmdrain();
      __syncthreads();
    }
  } else {
    for (int t = 0; t < nt; ++t) {
      stage(0, t);
      vmdrain();
      __syncthreads();
      compute(0);
      __syncthreads();
    }
  }

  if constexpr (!FUSE_LN) {
#pragma unroll
    for (int m = 0; m < MF; ++m) {
      int rowb = m0 + wr * (BMT / 2) + m * 16 + g * 4;
#pragma unroll
      for (int n = 0; n < 4; ++n) {
        int col = n0 + wc * 64 + n * 16 + fr;
        float bv = bias[col];
#pragma unroll
        for (int j = 0; j < 4; ++j) {
          float v = acc[m][n][j] + bv;
          if (RELU) v = fmaxf(v, 0.f);
          out[(size_t)(rowb + j) * N + col] = f2bf(v);
        }
      }
    }
  } else {
    // psum/psq scratch lives in the (now dead) A staging buffer
    float* psum = (float*)As;                 // [4][BMT]
    float* psq  = (float*)(As + 4 * BMT * 4); // [4][BMT]
#pragma unroll
    for (int m = 0; m < MF; ++m) {
      int rowb = wr * (BMT / 2) + m * 16 + g * 4;     // local row base
#pragma unroll
      for (int j = 0; j < 4; ++j) {
        float ps = 0.f, pq = 0.f;
#pragma unroll
        for (int n = 0; n < 4; ++n) {
          int col = wc * 64 + n * 16 + fr;
          float v = acc[m][n][j] + bias[col]
                  + bf2f(resid[(size_t)(m0 + rowb + j) * 256 + col]);
          acc[m][n][j] = v;
          ps += v; pq += v * v;
        }
#pragma unroll
        for (int d = 1; d < 16; d <<= 1) {
          ps += __shfl_xor(ps, d, 64);
          pq += __shfl_xor(pq, d, 64);
        }
        if (fr == 0) { psum[wc * BMT + rowb + j] = ps; psq[wc * BMT + rowb + j] = pq; }
      }
    }
    __syncthreads();
#pragma unroll
    for (int m = 0; m < MF; ++m) {
      int rowb = wr * (BMT / 2) + m * 16 + g * 4;
#pragma unroll
      for (int j = 0; j < 4; ++j) {
        int lr = rowb + j;
        float sm = psum[lr] + psum[BMT + lr] + psum[2 * BMT + lr] + psum[3 * BMT + lr];
        float sq = psq[lr] + psq[BMT + lr] + psq[2 * BMT + lr] + psq[3 * BMT + lr];
        float mean = sm * (1.f / 256.f);
        float var = sq * (1.f / 256.f) - mean * mean;
        float rs = rsqrtf(var + 1e-5f);
#pragma unroll
        for (int n = 0; n < 4; ++n) {
          int col = wc * 64 + n * 16 + fr;
          float v = (acc[m][n][j] - mean) * rs * lng[col] + lnb[col];
          out[(size_t)(m0 + lr) * 256 + col] = f2bf(v);
        }
      }
    }
  }
}

// ---------------------------------------------------------------------------
// MFMA windowed attention. One block per (n,b,head), 5 waves.
// Q read direct from global; K staged; Vt swizzle-transposed in LDS.
// NOTE: barrier between zero-fill and staging — they overlap in Vt and are
// written by different threads (the round-6 nondeterminism was this race).
// ---------------------------------------------------------------------------
constexpr int QKS = 40;    // K LDS row stride (ushorts)
constexpr int VTS = 104;   // Vt LDS row stride (d-major: [32][104])
constexpr int PS  = 104;   // P  LDS row stride

__device__ __forceinline__ int vslot(int d, int r) {
  int rc = r >> 3;
  int sw = (rc < 8) ? (rc ^ (d >> 3)) : rc;     // d>>3 in [0,4)
  return d * VTS + sw * 8 + (r & 7);
}

__global__ __launch_bounds__(320) void k_attn(
    const ushort* __restrict__ qkv, ushort* __restrict__ o,
    const int* __restrict__ lenp) {
  __shared__ __align__(16) ushort Ks[80 * QKS];
  __shared__ __align__(16) ushort Vt[32 * VTS];
  __shared__ __align__(16) ushort Pb[5 * 16 * PS];
  int L = lenp[0];
  int blk = blockIdx.x;
  int hh = blk & 7;
  int nb = blk >> 3;
  int b = nb & 1;
  int n = nb >> 1;
  int s0 = n - BLK; if (s0 < 0) s0 = 0;
  int e0 = n + BLK + 1; if (e0 > L) e0 = L;
  int vn = e0 - s0;
  int tid = threadIdx.x;

  for (int i = tid; i < 32 * VTS / 2; i += 320) ((uint*)Vt)[i] = 0;
  for (int i = tid; i < 15 * QKS / 2; i += 320)
    ((uint*)(Ks + 65 * QKS))[i] = 0;
  __syncthreads();   // zero-fill and staging overlap in Vt: must be ordered
  for (int e = tid; e < 65 * 4; e += 320) {
    int r = e >> 2, c = e & 3;
    const ushort* base = qkv + ((size_t)(n * WMAX + r) * BB + b) * (3 * DD) + hh * DH;
    *(uint4*)(Ks + r * QKS + c * 8) = *(const uint4*)(base + DD + c * 8);
    uint4 vv = *(const uint4*)(base + 2 * DD + c * 8);
    const ushort* vp = (const ushort*)&vv;
#pragma unroll
    for (int u = 0; u < 8; ++u) Vt[vslot(c * 8 + u, r)] = vp[u];
  }

  int w = tid >> 6, lane = tid & 63;
  int fr = lane & 15, g = lane >> 4;
  int q0 = w * 16;
  ushort* Pw = Pb + w * 16 * PS;

  // Q fragment direct from global (rows >64 clamped; their results unused)
  int qr_ld = q0 + fr; if (qr_ld > 64) qr_ld = 64;
  s16x8 aq = *(const s16x8*)(qkv + ((size_t)(n * WMAX + qr_ld) * BB + b) * (3 * DD)
                             + hh * DH + g * 8);
  __syncthreads();

  f32x4 sacc[5];
#pragma unroll
  for (int t = 0; t < 5; ++t) {
    s16x8 bk = *(const s16x8*)(Ks + (t * 16 + fr) * QKS + g * 8);
    f32x4 z = {0.f, 0.f, 0.f, 0.f};
    sacc[t] = __builtin_amdgcn_mfma_f32_16x16x32_bf16(aq, bk, z, 0, 0, 0);
  }
  const float scl = 0.17677669529663687f;
#pragma unroll
  for (int j = 0; j < 4; ++j) {
    float pv[5];
    float mx = -3e38f;
#pragma unroll
    for (int t = 0; t < 5; ++t) {
      bool ok = (t * 16 + fr) < vn;
      pv[t] = ok ? sacc[t][j] * scl : -3e38f;
      mx = fmaxf(mx, pv[t]);
    }
#pragma unroll
    for (int d = 1; d < 16; d <<= 1) mx = fmaxf(mx, __shfl_xor(mx, d, 64));
    float sum = 0.f;
#pragma unroll
    for (int t = 0; t < 5; ++t) {
      float e = ((t * 16 + fr) < vn) ? __expf(pv[t] - mx) : 0.f;
      pv[t] = e;
      sum += e;
    }
#pragma unroll
    for (int d = 1; d < 16; d <<= 1) sum += __shfl_xor(sum, d, 64);
    float inv = 1.f / sum;
#pragma unroll
    for (int t = 0; t < 5; ++t)
      Pw[(g * 4 + j) * PS + t * 16 + fr] = f2bf(pv[t] * inv);
  }
  {
    int zr = lane >> 2, zc = 80 + (lane & 3) * 4;
    *(uint2*)(Pw + zr * PS + zc) = make_uint2(0u, 0u);
  }
  __syncthreads();

  f32x4 oacc[2] = {};
#pragma unroll
  for (int k0 = 0; k0 < 3; ++k0) {
    s16x8 ap = *(const s16x8*)(Pw + fr * PS + k0 * 32 + g * 8);
#pragma unroll
    for (int nt = 0; nt < 2; ++nt) {
      s16x8 bv = *(const s16x8*)(Vt + vslot(nt * 16 + fr, k0 * 32 + g * 8));
      oacc[nt] = __builtin_amdgcn_mfma_f32_16x16x32_bf16(ap, bv, oacc[nt], 0, 0, 0);
    }
  }
#pragma unroll
  for (int nt = 0; nt < 2; ++nt) {
#pragma unroll
    for (int j = 0; j < 4; ++j) {
      int qr = q0 + g * 4 + j;
      if (qr < WMAX)
        o[((size_t)(n * WMAX + qr) * BB + b) * DD + hh * DH + nt * 16 + fr] =
            f2bf(oacc[nt][j]);
    }
  }
}

// ---------------------------------------------------------------------------
// Final hierarchical softmax-gather (h bf16)
// ---------------------------------------------------------------------------
__global__ __launch_bounds__(256) void k_final(
    const ushort* __restrict__ h, const float* __restrict__ kp,
    float* __restrict__ out, const int* __restrict__ lenp) {
  int L = lenp[0];
  int t = blockIdx.x >> 1, b = blockIdx.x & 1;
  float hsc = (float)L / (float)NN;
  int nlo = t - BLK; if (nlo < 0) nlo = 0;
  int nhi = t + BLK; if (nhi > NN - 1) nhi = NN - 1;
  float mx = -3e38f;
  for (int n = nlo; n <= nhi; ++n) {
    float kp0 = kp[(n * BB + b) * 2 + 0];
    float kp1 = kp[(n * BB + b) * 2 + 1];
    float dif = (float)t - (float)n * hsc - kp0;
    float lg = -dif * dif * __expf(kp1);
    mx = fmaxf(mx, lg);
  }
  float sum = 0.f, acc = 0.f;
  int c = threadIdx.x;
  for (int n = nlo; n <= nhi; ++n) {
    float kp0 = kp[(n * BB + b) * 2 + 0];
    float kp1 = kp[(n * BB + b) * 2 + 1];
    float dif = (float)t - (float)n * hsc - kp0;
    float lg = -dif * dif * __expf(kp1);
    float p = __expf(lg - mx);
    sum += p;
    int st = n - BLK; if (st < 0) st = 0;
    int w = t - st;
    acc += p * bf2f(h[(size_t)((n * WMAX + w) * BB + b) * DD + c]);
  }
  out[(size_t)(t * BB + b) * DD + c] = acc / sum;
}

// ---------------------------------------------------------------------------
extern "C" void kernel_launch(void* const* d_in, const int* in_sizes, int n_in,
                              void* d_out, int out_size, void* d_ws, size_t ws_size,
                              hipStream_t stream) {
  const float* inputs = (const float*)d_in[0];
  const float* in_W1  = (const float*)d_in[1];
  const float* in_b1  = (const float*)d_in[2];
  const float* in_W2  = (const float*)d_in[3];
  const float* in_b2  = (const float*)d_in[4];
  const float* k_W1   = (const float*)d_in[5];
  const float* k_b1   = (const float*)d_in[6];
  const float* k_W2   = (const float*)d_in[7];
  const float* k_b2   = (const float*)d_in[8];
  const float* Wqkv   = (const float*)d_in[9];
  const float* bqkv   = (const float*)d_in[10];
  const float* Wo     = (const float*)d_in[11];
  const float* bo     = (const float*)d_in[12];
  const float* ln1_g  = (const float*)d_in[13];
  const float* ln1_b  = (const float*)d_in[14];
  const float* W1     = (const float*)d_in[15];
  const float* b1     = (const float*)d_in[16];
  const float* W2     = (const float*)d_in[17];
  const float* b2     = (const float*)d_in[18];
  const float* ln2_g  = (const float*)d_in[19];
  const float* ln2_b  = (const float*)d_in[20];
  const int*   lenp   = (const int*)d_in[21];
  float* out = (float*)d_out;
  (void)in_sizes; (void)n_in; (void)ws_size;

  ushort* wsu = (ushort*)d_ws;
  size_t off = 0;
  auto alloc = [&](size_t nelem) { ushort* p = wsu + off; off += (nelem + 7) & ~7ull; return p; };
  ushort* inW1t = alloc((size_t)DFF * DIN);
  ushort* inW2t = alloc((size_t)DD * DFF);
  ushort* Wqkvt = alloc((size_t)NL * 3 * DD * DD);
  ushort* Wot   = alloc((size_t)NL * DD * DD);
  ushort* W1t   = alloc((size_t)NL * DFF * DD);
  ushort* W2t   = alloc((size_t)NL * DD * DFF);
  ushort* x     = alloc((size_t)RROWS * DIN);
  ushort* tq    = alloc((size_t)RROWS * DFF);
  ushort* hb    = alloc((size_t)RROWS * DD);
  ushort* ob    = alloc((size_t)RROWS * DD);
  float*  kp    = (float*)(wsu + off);

  int L = out_size / (BB * DD);                      // 160

  TPack tp;
  tp.d[0] = {in_W1, inW1t, DIN, DFF};
  tp.d[1] = {in_W2, inW2t, DFF, DD};
  tp.d[2] = {Wqkv,                        Wqkvt,                       DD, 3 * DD};
  tp.d[3] = {Wqkv + (size_t)DD * 3 * DD,  Wqkvt + (size_t)3 * DD * DD, DD, 3 * DD};
  tp.d[4] = {Wo,                    Wot,                   DD, DD};
  tp.d[5] = {Wo + (size_t)DD * DD,  Wot + (size_t)DD * DD, DD, DD};
  tp.d[6] = {W1,                      W1t,                    DD, DFF};
  tp.d[7] = {W1 + (size_t)DD * DFF,   W1t + (size_t)DFF * DD, DD, DFF};
  tp.d[8] = {W2,                      W2t,                    DFF, DD};
  tp.d[9] = {W2 + (size_t)DFF * DD,   W2t + (size_t)DD * DFF, DFF, DD};

  k_prep<<<WCONV_TILES + BX_BLOCKS + NN * BB, 256, 0, stream>>>(
      tp, inputs, x, k_W1, k_b1, k_W2, k_b2, kp);

  // input MLP
  k_gemm8<128, 1, 0, 0><<<dim3(RROWS / 128, 4), 512, 0, stream>>>(
      x, inW1t, in_b1, nullptr, nullptr, nullptr, tq, DFF, DIN);
  k_gemm8<64, 0, 0, 1><<<dim3(RROWS / 64, 1), 512, 0, stream>>>(
      tq, inW2t, in_b2, nullptr, nullptr, nullptr, hb, DD, DFF);

  for (int l = 0; l < NL; ++l) {
    k_gemm8<128, 0, 0, 0><<<dim3(RROWS / 128, 3), 512, 0, stream>>>(
        hb, Wqkvt + (size_t)l * 3 * DD * DD, bqkv + (size_t)l * 3 * DD,
        nullptr, nullptr, nullptr, tq, 3 * DD, DD);
    k_attn<<<NN * BB * NH, 320, 0, stream>>>(tq, ob, lenp);
    k_gemm8<64, 0, 1, 1><<<dim3(RROWS / 64, 1), 512, 0, stream>>>(
        ob, Wot + (size_t)l * DD * DD, bo + (size_t)l * DD, hb,
        ln1_g + (size_t)l * DD, ln1_b + (size_t)l * DD, hb, DD, DD);
    k_gemm8<128, 1, 0, 0><<<dim3(RROWS / 128, 4), 512, 0, stream>>>(
        hb, W1t + (size_t)l * DFF * DD, b1 + (size_t)l * DFF,
        nullptr, nullptr, nullptr, tq, DFF, DD);
    k_gemm8<64, 0, 1, 1><<<dim3(RROWS / 64, 1), 512, 0, stream>>>(
        tq, W2t + (size_t)l * DD * DFF, b2 + (size_t)l * DD, hb,
        ln2_g + (size_t)l * DD, ln2_b + (size_t)l * DD, hb, DD, DFF);
  }
  k_final<<<L * BB, 256, 0, stream>>>(hb, kp, out, lenp);
}